// Round 2
// baseline (1942.570 us; speedup 1.0000x reference)
//
#include <hip/hip_runtime.h>
#include <hip/hip_bf16.h>
#include <math.h>

#define NN 40000
#define NE 640000
#define NG 256
#define FD 128

__device__ __forceinline__ float sigf(float x) { return 1.f / (1.f + __expf(-x)); }

// ---- degree per dst node (float) + nodes-per-graph histogram ----
__global__ void k_hist(const int* __restrict__ ei, const int* __restrict__ batch,
                       float* __restrict__ deg, int* __restrict__ gcnt) {
    int i = blockIdx.x * blockDim.x + threadIdx.x;
    if (i < NE) atomicAdd(&deg[ei[NE + i]], 1.0f);
    if (i < NN) atomicAdd(&gcnt[batch[i]], 1);
}

// ---- exclusive scan of 256 graph counts -> gptr[257] (batch is sorted) ----
__global__ void k_scan(const int* __restrict__ gcnt, int* __restrict__ gptr) {
    __shared__ int s[NG];
    int t = threadIdx.x;
    s[t] = gcnt[t];
    __syncthreads();
    for (int off = 1; off < NG; off <<= 1) {
        int v = (t >= off) ? s[t - off] : 0;
        __syncthreads();
        s[t] += v;
        __syncthreads();
    }
    gptr[t + 1] = s[t];
    if (t == 0) gptr[0] = 0;
}

// ---- scatter-add aggregation: one wave per edge, 2 dims per lane (fp32) ----
__global__ void k_agg(const float* __restrict__ feat, const int* __restrict__ ei,
                      float* __restrict__ agg) {
    int w = (blockIdx.x * blockDim.x + threadIdx.x) >> 6;
    int lane = threadIdx.x & 63;
    if (w >= NE) return;
    int src = ei[w];
    int dst = ei[NE + w];
    float2 v = ((const float2*)(feat + (size_t)src * FD))[lane];
    float* dp = agg + (size_t)dst * FD + 2 * lane;
    atomicAdd(dp, v.x);
    atomicAdd(dp + 1, v.y);
}

// ---- combine: out = mean @ Wl^T + bl + x @ Wr^T, then BN(eval) + ReLU (fp32) ----
// 8 nodes per block, 128 threads (thread t owns output dim t).
// NOTE: safe for outf == feat (in-place): each block stages its own 8 rows in
// LDS before any write, and blocks touch disjoint rows.
__global__ __launch_bounds__(128) void k_combine(
    const float* __restrict__ feat, const float* __restrict__ agg,
    const float* __restrict__ deg,
    const float* __restrict__ Wl, const float* __restrict__ bl,
    const float* __restrict__ Wr,
    const float* __restrict__ gam, const float* __restrict__ bet,
    const float* __restrict__ rme, const float* __restrict__ rva,
    float* __restrict__ outf)
{
    __shared__ float sm[8][FD];
    __shared__ float sx[8][FD];
    int t = threadIdx.x;
    int node0 = blockIdx.x * 8;
    for (int n = 0; n < 8; n++) {
        int node = node0 + n;
        float dv = fmaxf(deg[node], 1.0f);
        sm[n][t] = agg[(size_t)node * FD + t] * (1.0f / dv);
        sx[n][t] = feat[(size_t)node * FD + t];
    }
    __syncthreads();
    float acc[8];
#pragma unroll
    for (int n = 0; n < 8; n++) acc[n] = 0.f;
    const float* wl = Wl + (size_t)t * FD;
    const float* wr = Wr + (size_t)t * FD;
    for (int k = 0; k < FD; k += 4) {
        float4 ul = *(const float4*)(wl + k);
        float4 ur = *(const float4*)(wr + k);
#pragma unroll
        for (int n = 0; n < 8; n++) {
            float a = acc[n];
            a += sm[n][k + 0] * ul.x + sx[n][k + 0] * ur.x;
            a += sm[n][k + 1] * ul.y + sx[n][k + 1] * ur.y;
            a += sm[n][k + 2] * ul.z + sx[n][k + 2] * ur.z;
            a += sm[n][k + 3] * ul.w + sx[n][k + 3] * ur.w;
            acc[n] = a;
        }
    }
    float bb = bl[t];
    float scale = gam[t] * rsqrtf(rva[t] + 1e-5f);
    float rm = rme[t];
    float bt = bet[t];
#pragma unroll
    for (int n = 0; n < 8; n++) {
        float y = acc[n] + bb;
        float z = scale * (y - rm) + bt;
        outf[(size_t)(node0 + n) * FD + t] = fmaxf(z, 0.f);
    }
}

// ---- fused set2set (3 steps) + final projection; one block (256 thr) per graph ----
__global__ __launch_bounds__(256) void k_s2s(
    const float* __restrict__ h2, const int* __restrict__ gptr,
    const float* __restrict__ Wih, const float* __restrict__ Whh,
    const float* __restrict__ bih, const float* __restrict__ bhh,
    const float* __restrict__ Wp, const float* __restrict__ bp,
    float* __restrict__ out)
{
    int b = blockIdx.x;
    int t = threadIdx.x;
    int wave = t >> 6, lane = t & 63;
    __shared__ float qstar[256];
    __shared__ float hs[FD], cs[FD];
    __shared__ float gates[512];
    __shared__ float red[4 * FD];
    __shared__ float wden[4], wmax[4];

    qstar[t] = 0.f;
    if (t < FD) { hs[t] = 0.f; cs[t] = 0.f; }
    __syncthreads();

    int start = gptr[b], end = gptr[b + 1];

    for (int step = 0; step < 3; step++) {
        // LSTM gates: thread t computes rows t and t+256 of [512]
#pragma unroll
        for (int gi = 0; gi < 2; gi++) {
            int row = t + gi * 256;
            const float* wi = Wih + (size_t)row * 256;
            const float* wh = Whh + (size_t)row * 128;
            float acc = bih[row] + bhh[row];
            for (int k = 0; k < 256; k += 4) {
                float4 u = *(const float4*)(wi + k);
                acc += qstar[k] * u.x + qstar[k + 1] * u.y +
                       qstar[k + 2] * u.z + qstar[k + 3] * u.w;
            }
            for (int k = 0; k < 128; k += 4) {
                float4 u = *(const float4*)(wh + k);
                acc += hs[k] * u.x + hs[k + 1] * u.y +
                       hs[k + 2] * u.z + hs[k + 3] * u.w;
            }
            gates[row] = acc;
        }
        __syncthreads();
        if (t < FD) {
            float ig = gates[t], fg = gates[128 + t], gg = gates[256 + t], og = gates[384 + t];
            float c = sigf(fg) * cs[t] + sigf(ig) * tanhf(gg);
            float h = sigf(og) * tanhf(c);
            cs[t] = c; hs[t] = h;
        }
        __syncthreads();

        // attention pass 1: per-node dot(h2[n], q) -> segment max
        float m = -INFINITY;
        for (int n = start + wave; n < end; n += 4) {
            float2 v = ((const float2*)(h2 + (size_t)n * FD))[lane];
            float d = v.x * hs[2 * lane] + v.y * hs[2 * lane + 1];
#pragma unroll
            for (int off = 32; off; off >>= 1) d += __shfl_xor(d, off);
            m = fmaxf(m, d);
        }
        wmax[wave] = m;
        __syncthreads();
        float emax = fmaxf(fmaxf(wmax[0], wmax[1]), fmaxf(wmax[2], wmax[3]));

        // pass 2: softmax-weighted sum (recompute dot; avoids global round-trip)
        float r0 = 0.f, r1 = 0.f, den = 0.f;
        for (int n = start + wave; n < end; n += 4) {
            float2 v = ((const float2*)(h2 + (size_t)n * FD))[lane];
            float d = v.x * hs[2 * lane] + v.y * hs[2 * lane + 1];
#pragma unroll
            for (int off = 32; off; off >>= 1) d += __shfl_xor(d, off);
            float a = __expf(d - emax);
            r0 += a * v.x; r1 += a * v.y; den += a;
        }
        red[wave * FD + 2 * lane] = r0;
        red[wave * FD + 2 * lane + 1] = r1;
        wden[wave] = den;
        __syncthreads();
        if (t < FD) {
            float r = red[t] + red[FD + t] + red[2 * FD + t] + red[3 * FD + t];
            float ds = wden[0] + wden[1] + wden[2] + wden[3];
            float rn = (ds > 0.f) ? r / ds : 0.f;
            qstar[t] = hs[t];
            qstar[128 + t] = rn;
        }
        __syncthreads();
    }

    // final projection: out[b, t] = bp[t] + sum_k qstar[k] * Wp[t, k]
    if (t < FD) {
        const float* wrow = Wp + (size_t)t * 256;
        float acc = bp[t];
        for (int k = 0; k < 256; k += 4) {
            float4 u = *(const float4*)(wrow + k);
            acc += qstar[k] * u.x + qstar[k + 1] * u.y +
                   qstar[k + 2] * u.z + qstar[k + 3] * u.w;
        }
        out[(size_t)b * FD + t] = acc;
    }
}

__global__ void k_zero_out(float* __restrict__ out, int n) {
    int i = blockIdx.x * blockDim.x + threadIdx.x;
    if (i < n) out[i] = 0.f;
}

extern "C" void kernel_launch(void* const* d_in, const int* in_sizes, int n_in,
                              void* d_out, int out_size, void* d_ws, size_t ws_size,
                              hipStream_t stream) {
    const float* x   = (const float*)d_in[0];
    const int*  ei    = (const int*)d_in[1];
    const int*  batch = (const int*)d_in[2];
    const float* W1l = (const float*)d_in[3];
    const float* b1l = (const float*)d_in[4];
    const float* W1r = (const float*)d_in[5];
    const float* g1  = (const float*)d_in[6];
    const float* be1 = (const float*)d_in[7];
    const float* rm1 = (const float*)d_in[8];
    const float* rv1 = (const float*)d_in[9];
    const float* W2l = (const float*)d_in[10];
    const float* b2l = (const float*)d_in[11];
    const float* W2r = (const float*)d_in[12];
    const float* g2  = (const float*)d_in[13];
    const float* be2 = (const float*)d_in[14];
    const float* rm2 = (const float*)d_in[15];
    const float* rv2 = (const float*)d_in[16];
    const float* Wih = (const float*)d_in[17];
    const float* Whh = (const float*)d_in[18];
    const float* bih = (const float*)d_in[19];
    const float* bhh = (const float*)d_in[20];
    const float* Wp  = (const float*)d_in[21];
    const float* bp  = (const float*)d_in[22];
    float* out = (float*)d_out;

    auto al = [](size_t s) { return (s + 255) & ~(size_t)255; };
    size_t off_deg  = 0;
    size_t off_gcnt = off_deg  + al((size_t)NN * 4);
    size_t off_gptr = off_gcnt + al((size_t)NG * 4);
    size_t off_agg  = off_gptr + al((size_t)(NG + 1) * 4);
    size_t off_h    = off_agg  + al((size_t)NN * FD * 4);
    size_t need     = off_h    + al((size_t)NN * FD * 4);

    if (ws_size < need) {
        // diagnostic signature: clean zero output (absmax == max|ref|)
        k_zero_out<<<(out_size + 255) / 256, 256, 0, stream>>>(out, out_size);
        return;
    }

    char* p = (char*)d_ws;
    float* deg = (float*)(p + off_deg);
    int* gcnt  = (int*)(p + off_gcnt);
    int* gptr  = (int*)(p + off_gptr);
    float* agg = (float*)(p + off_agg);
    float* h   = (float*)(p + off_h);   // h1 then (in-place) h2

    hipMemsetAsync(deg, 0, (size_t)NN * 4, stream);
    hipMemsetAsync(gcnt, 0, (size_t)NG * 4, stream);
    k_hist<<<(NE + 255) / 256, 256, 0, stream>>>(ei, batch, deg, gcnt);
    k_scan<<<1, NG, 0, stream>>>(gcnt, gptr);

    // layer 1: x -> h
    hipMemsetAsync(agg, 0, (size_t)NN * FD * 4, stream);
    k_agg<<<NE / 4, 256, 0, stream>>>(x, ei, agg);
    k_combine<<<NN / 8, 128, 0, stream>>>(x, agg, deg, W1l, b1l, W1r, g1, be1, rm1, rv1, h);

    // layer 2: h -> h (in-place safe, see k_combine note)
    hipMemsetAsync(agg, 0, (size_t)NN * FD * 4, stream);
    k_agg<<<NE / 4, 256, 0, stream>>>(h, ei, agg);
    k_combine<<<NN / 8, 128, 0, stream>>>(h, agg, deg, W2l, b2l, W2r, g2, be2, rm2, rv2, h);

    // set2set + projection
    k_s2s<<<NG, 256, 0, stream>>>(h, gptr, Wih, Whh, bih, bhh, Wp, bp, out);
}

// Round 3
// 1129.795 us; speedup vs baseline: 1.7194x; 1.7194x over previous
//
#include <hip/hip_runtime.h>
#include <hip/hip_bf16.h>
#include <math.h>

#define NN 40000
#define NE 640000
#define NG 256
#define FD 128

__device__ __forceinline__ float sigf(float x) { return 1.f / (1.f + __expf(-x)); }

// ---- degree histogram per dst node + nodes-per-graph histogram ----
__global__ void k_hist(const int* __restrict__ ei, const int* __restrict__ batch,
                       int* __restrict__ dcnt, int* __restrict__ gcnt) {
    int i = blockIdx.x * blockDim.x + threadIdx.x;
    if (i < NE) atomicAdd(&dcnt[ei[NE + i]], 1);
    if (i < NN) atomicAdd(&gcnt[batch[i]], 1);
}

// ---- exclusive scan of 40000 node degrees -> rowptr[NN+1]; 1 block, 1024 thr ----
#define SCH 40  // 1024 * 40 = 40960 >= NN
__global__ __launch_bounds__(1024) void k_scan_nodes(const int* __restrict__ dcnt,
                                                     int* __restrict__ rowptr) {
    __shared__ int s[1024];
    int t = threadIdx.x;
    int base = t * SCH;
    int local = 0;
#pragma unroll
    for (int i = 0; i < SCH; i++) {
        int idx = base + i;
        if (idx < NN) local += dcnt[idx];
    }
    s[t] = local;
    __syncthreads();
    for (int off = 1; off < 1024; off <<= 1) {
        int v = (t >= off) ? s[t - off] : 0;
        __syncthreads();
        s[t] += v;
        __syncthreads();
    }
    int run = s[t] - local;  // exclusive prefix
#pragma unroll
    for (int i = 0; i < SCH; i++) {
        int idx = base + i;
        if (idx < NN) { rowptr[idx] = run; run += dcnt[idx]; }
    }
    if (t == 0) rowptr[NN] = s[1023];
}

// ---- exclusive scan of 256 graph counts -> gptr[257] (batch is sorted) ----
__global__ void k_scan(const int* __restrict__ gcnt, int* __restrict__ gptr) {
    __shared__ int s[NG];
    int t = threadIdx.x;
    s[t] = gcnt[t];
    __syncthreads();
    for (int off = 1; off < NG; off <<= 1) {
        int v = (t >= off) ? s[t - off] : 0;
        __syncthreads();
        s[t] += v;
        __syncthreads();
    }
    gptr[t + 1] = s[t];
    if (t == 0) gptr[0] = 0;
}

// ---- bucket edge sources by dst: srcs[rowptr[dst]...] = src ----
__global__ void k_permute(const int* __restrict__ ei, const int* __restrict__ rowptr,
                          int* __restrict__ cursor, int* __restrict__ srcs) {
    int i = blockIdx.x * blockDim.x + threadIdx.x;
    if (i >= NE) return;
    int dst = ei[NE + i];
    int pos = atomicAdd(&cursor[dst], 1);
    srcs[rowptr[dst] + pos] = ei[i];
}

// ---- fused gather-aggregate + combine + BN + ReLU ----
// out = (sum_j feat[srcs]/max(deg,1)) @ Wl^T + bl + feat @ Wr^T -> BN -> ReLU
// 8 nodes per block, 128 threads (thread t owns dim t). NOT in-place safe
// (reads neighbor rows while other blocks write theirs) -> distinct in/out.
__global__ __launch_bounds__(128) void k_combine(
    const float* __restrict__ feat, const int* __restrict__ srcs,
    const int* __restrict__ rowptr,
    const float* __restrict__ Wl, const float* __restrict__ bl,
    const float* __restrict__ Wr,
    const float* __restrict__ gam, const float* __restrict__ bet,
    const float* __restrict__ rme, const float* __restrict__ rva,
    float* __restrict__ outf)
{
    __shared__ float sm[8][FD];
    __shared__ float sx[8][FD];
    int t = threadIdx.x;
    int node0 = blockIdx.x * 8;
    for (int n = 0; n < 8; n++) {
        int node = node0 + n;
        int s0 = rowptr[node], e0 = rowptr[node + 1];
        float a0 = 0.f, a1 = 0.f;
        int i = s0;
        for (; i + 1 < e0; i += 2) {
            a0 += feat[(size_t)srcs[i] * FD + t];
            a1 += feat[(size_t)srcs[i + 1] * FD + t];
        }
        if (i < e0) a0 += feat[(size_t)srcs[i] * FD + t];
        float dv = fmaxf((float)(e0 - s0), 1.0f);
        sm[n][t] = (a0 + a1) * (1.0f / dv);
        sx[n][t] = feat[(size_t)node * FD + t];
    }
    __syncthreads();
    float acc[8];
#pragma unroll
    for (int n = 0; n < 8; n++) acc[n] = 0.f;
    const float* wl = Wl + (size_t)t * FD;
    const float* wr = Wr + (size_t)t * FD;
    for (int k = 0; k < FD; k += 4) {
        float4 ul = *(const float4*)(wl + k);
        float4 ur = *(const float4*)(wr + k);
#pragma unroll
        for (int n = 0; n < 8; n++) {
            float a = acc[n];
            a += sm[n][k + 0] * ul.x + sx[n][k + 0] * ur.x;
            a += sm[n][k + 1] * ul.y + sx[n][k + 1] * ur.y;
            a += sm[n][k + 2] * ul.z + sx[n][k + 2] * ur.z;
            a += sm[n][k + 3] * ul.w + sx[n][k + 3] * ur.w;
            acc[n] = a;
        }
    }
    float bb = bl[t];
    float scale = gam[t] * rsqrtf(rva[t] + 1e-5f);
    float rm = rme[t];
    float bt = bet[t];
#pragma unroll
    for (int n = 0; n < 8; n++) {
        float y = acc[n] + bb;
        float z = scale * (y - rm) + bt;
        outf[(size_t)(node0 + n) * FD + t] = fmaxf(z, 0.f);
    }
}

// ---- fused set2set (3 steps) + final projection; one block (256 thr) per graph ----
__global__ __launch_bounds__(256) void k_s2s(
    const float* __restrict__ h2, const int* __restrict__ gptr,
    const float* __restrict__ Wih, const float* __restrict__ Whh,
    const float* __restrict__ bih, const float* __restrict__ bhh,
    const float* __restrict__ Wp, const float* __restrict__ bp,
    float* __restrict__ out)
{
    int b = blockIdx.x;
    int t = threadIdx.x;
    int wave = t >> 6, lane = t & 63;
    __shared__ float qstar[256];
    __shared__ float hs[FD], cs[FD];
    __shared__ float gates[512];
    __shared__ float red[4 * FD];
    __shared__ float wden[4], wmax[4];

    qstar[t] = 0.f;
    if (t < FD) { hs[t] = 0.f; cs[t] = 0.f; }
    __syncthreads();

    int start = gptr[b], end = gptr[b + 1];

    for (int step = 0; step < 3; step++) {
#pragma unroll
        for (int gi = 0; gi < 2; gi++) {
            int row = t + gi * 256;
            const float* wi = Wih + (size_t)row * 256;
            const float* wh = Whh + (size_t)row * 128;
            float acc = bih[row] + bhh[row];
            for (int k = 0; k < 256; k += 4) {
                float4 u = *(const float4*)(wi + k);
                acc += qstar[k] * u.x + qstar[k + 1] * u.y +
                       qstar[k + 2] * u.z + qstar[k + 3] * u.w;
            }
            for (int k = 0; k < 128; k += 4) {
                float4 u = *(const float4*)(wh + k);
                acc += hs[k] * u.x + hs[k + 1] * u.y +
                       hs[k + 2] * u.z + hs[k + 3] * u.w;
            }
            gates[row] = acc;
        }
        __syncthreads();
        if (t < FD) {
            float ig = gates[t], fg = gates[128 + t], gg = gates[256 + t], og = gates[384 + t];
            float c = sigf(fg) * cs[t] + sigf(ig) * tanhf(gg);
            float h = sigf(og) * tanhf(c);
            cs[t] = c; hs[t] = h;
        }
        __syncthreads();

        float m = -INFINITY;
        for (int n = start + wave; n < end; n += 4) {
            float2 v = ((const float2*)(h2 + (size_t)n * FD))[lane];
            float d = v.x * hs[2 * lane] + v.y * hs[2 * lane + 1];
#pragma unroll
            for (int off = 32; off; off >>= 1) d += __shfl_xor(d, off);
            m = fmaxf(m, d);
        }
        wmax[wave] = m;
        __syncthreads();
        float emax = fmaxf(fmaxf(wmax[0], wmax[1]), fmaxf(wmax[2], wmax[3]));

        float r0 = 0.f, r1 = 0.f, den = 0.f;
        for (int n = start + wave; n < end; n += 4) {
            float2 v = ((const float2*)(h2 + (size_t)n * FD))[lane];
            float d = v.x * hs[2 * lane] + v.y * hs[2 * lane + 1];
#pragma unroll
            for (int off = 32; off; off >>= 1) d += __shfl_xor(d, off);
            float a = __expf(d - emax);
            r0 += a * v.x; r1 += a * v.y; den += a;
        }
        red[wave * FD + 2 * lane] = r0;
        red[wave * FD + 2 * lane + 1] = r1;
        wden[wave] = den;
        __syncthreads();
        if (t < FD) {
            float r = red[t] + red[FD + t] + red[2 * FD + t] + red[3 * FD + t];
            float ds = wden[0] + wden[1] + wden[2] + wden[3];
            float rn = (ds > 0.f) ? r / ds : 0.f;
            qstar[t] = hs[t];
            qstar[128 + t] = rn;
        }
        __syncthreads();
    }

    if (t < FD) {
        const float* wrow = Wp + (size_t)t * 256;
        float acc = bp[t];
        for (int k = 0; k < 256; k += 4) {
            float4 u = *(const float4*)(wrow + k);
            acc += qstar[k] * u.x + qstar[k + 1] * u.y +
                   qstar[k + 2] * u.z + qstar[k + 3] * u.w;
        }
        out[(size_t)b * FD + t] = acc;
    }
}

__global__ void k_zero_out(float* __restrict__ out, int n) {
    int i = blockIdx.x * blockDim.x + threadIdx.x;
    if (i < n) out[i] = 0.f;
}

extern "C" void kernel_launch(void* const* d_in, const int* in_sizes, int n_in,
                              void* d_out, int out_size, void* d_ws, size_t ws_size,
                              hipStream_t stream) {
    const float* x   = (const float*)d_in[0];
    const int*  ei    = (const int*)d_in[1];
    const int*  batch = (const int*)d_in[2];
    const float* W1l = (const float*)d_in[3];
    const float* b1l = (const float*)d_in[4];
    const float* W1r = (const float*)d_in[5];
    const float* g1  = (const float*)d_in[6];
    const float* be1 = (const float*)d_in[7];
    const float* rm1 = (const float*)d_in[8];
    const float* rv1 = (const float*)d_in[9];
    const float* W2l = (const float*)d_in[10];
    const float* b2l = (const float*)d_in[11];
    const float* W2r = (const float*)d_in[12];
    const float* g2  = (const float*)d_in[13];
    const float* be2 = (const float*)d_in[14];
    const float* rm2 = (const float*)d_in[15];
    const float* rv2 = (const float*)d_in[16];
    const float* Wih = (const float*)d_in[17];
    const float* Whh = (const float*)d_in[18];
    const float* bih = (const float*)d_in[19];
    const float* bhh = (const float*)d_in[20];
    const float* Wp  = (const float*)d_in[21];
    const float* bp  = (const float*)d_in[22];
    float* out = (float*)d_out;

    auto al = [](size_t s) { return (s + 255) & ~(size_t)255; };
    size_t off_dcnt = 0;
    size_t off_cur  = off_dcnt + al((size_t)NN * 4);
    size_t off_rp   = off_cur  + al((size_t)NN * 4);
    size_t off_gcnt = off_rp   + al((size_t)(NN + 1) * 4);
    size_t off_gptr = off_gcnt + al((size_t)NG * 4);
    size_t off_srcs = off_gptr + al((size_t)(NG + 1) * 4);
    size_t off_h1   = off_srcs + al((size_t)NE * 4);
    size_t off_h2   = off_h1   + al((size_t)NN * FD * 4);
    size_t need     = off_h2   + al((size_t)NN * FD * 4);

    if (ws_size < need) {
        k_zero_out<<<(out_size + 255) / 256, 256, 0, stream>>>(out, out_size);
        return;
    }

    char* p = (char*)d_ws;
    int* dcnt   = (int*)(p + off_dcnt);
    int* cursor = (int*)(p + off_cur);
    int* rowptr = (int*)(p + off_rp);
    int* gcnt   = (int*)(p + off_gcnt);
    int* gptr   = (int*)(p + off_gptr);
    int* srcs   = (int*)(p + off_srcs);
    float* h1   = (float*)(p + off_h1);
    float* h2   = (float*)(p + off_h2);

    hipMemsetAsync(dcnt, 0, (size_t)NN * 4, stream);
    hipMemsetAsync(cursor, 0, (size_t)NN * 4, stream);
    hipMemsetAsync(gcnt, 0, (size_t)NG * 4, stream);

    // CSR build
    k_hist<<<(NE + 255) / 256, 256, 0, stream>>>(ei, batch, dcnt, gcnt);
    k_scan_nodes<<<1, 1024, 0, stream>>>(dcnt, rowptr);
    k_scan<<<1, NG, 0, stream>>>(gcnt, gptr);
    k_permute<<<(NE + 255) / 256, 256, 0, stream>>>(ei, rowptr, cursor, srcs);

    // layer 1: x -> h1 ; layer 2: h1 -> h2
    k_combine<<<NN / 8, 128, 0, stream>>>(x, srcs, rowptr, W1l, b1l, W1r, g1, be1, rm1, rv1, h1);
    k_combine<<<NN / 8, 128, 0, stream>>>(h1, srcs, rowptr, W2l, b2l, W2r, g2, be2, rm2, rv2, h2);

    // set2set + projection
    k_s2s<<<NG, 256, 0, stream>>>(h2, gptr, Wih, Whh, bih, bhh, Wp, bp, out);
}

// Round 4
// 791.247 us; speedup vs baseline: 2.4551x; 1.4279x over previous
//
#include <hip/hip_runtime.h>
#include <hip/hip_bf16.h>
#include <math.h>

#define NN 40000
#define NE 640000
#define NG 256
#define FD 128

__device__ __forceinline__ float sigf(float x) { return 1.f / (1.f + __expf(-x)); }

// ---- degree histogram per dst node + nodes-per-graph histogram ----
__global__ void k_hist(const int* __restrict__ ei, const int* __restrict__ batch,
                       int* __restrict__ dcnt, int* __restrict__ gcnt) {
    int i = blockIdx.x * blockDim.x + threadIdx.x;
    if (i < NE) atomicAdd(&dcnt[ei[NE + i]], 1);
    if (i < NN) atomicAdd(&gcnt[batch[i]], 1);
}

// ---- exclusive scan of 40000 node degrees -> rowptr[NN+1]; 1 block, 1024 thr ----
#define SCH 40  // 1024 * 40 = 40960 >= NN
__global__ __launch_bounds__(1024) void k_scan_nodes(const int* __restrict__ dcnt,
                                                     int* __restrict__ rowptr) {
    __shared__ int s[1024];
    int t = threadIdx.x;
    int base = t * SCH;
    int local = 0;
#pragma unroll
    for (int i = 0; i < SCH; i++) {
        int idx = base + i;
        if (idx < NN) local += dcnt[idx];
    }
    s[t] = local;
    __syncthreads();
    for (int off = 1; off < 1024; off <<= 1) {
        int v = (t >= off) ? s[t - off] : 0;
        __syncthreads();
        s[t] += v;
        __syncthreads();
    }
    int run = s[t] - local;  // exclusive prefix
#pragma unroll
    for (int i = 0; i < SCH; i++) {
        int idx = base + i;
        if (idx < NN) { rowptr[idx] = run; run += dcnt[idx]; }
    }
    if (t == 0) rowptr[NN] = s[1023];
}

// ---- exclusive scan of 256 graph counts -> gptr[257] (batch is sorted) ----
__global__ void k_scan(const int* __restrict__ gcnt, int* __restrict__ gptr) {
    __shared__ int s[NG];
    int t = threadIdx.x;
    s[t] = gcnt[t];
    __syncthreads();
    for (int off = 1; off < NG; off <<= 1) {
        int v = (t >= off) ? s[t - off] : 0;
        __syncthreads();
        s[t] += v;
        __syncthreads();
    }
    gptr[t + 1] = s[t];
    if (t == 0) gptr[0] = 0;
}

// ---- bucket edge sources by dst: srcs[rowptr[dst]...] = src ----
__global__ void k_permute(const int* __restrict__ ei, const int* __restrict__ rowptr,
                          int* __restrict__ cursor, int* __restrict__ srcs) {
    int i = blockIdx.x * blockDim.x + threadIdx.x;
    if (i >= NE) return;
    int dst = ei[NE + i];
    int pos = atomicAdd(&cursor[dst], 1);
    srcs[rowptr[dst] + pos] = ei[i];
}

// ---- fused gather-aggregate + combine + BN + ReLU ----
// 8 nodes per block, 256 threads. Gather: one node per half-wave (32 lanes,
// float4 per lane), 4-way unrolled neighbor loads for MLP. GEMV: thread
// (d = t&127, p = t>>7) accumulates 4 nodes.
__global__ __launch_bounds__(256) void k_combine(
    const float* __restrict__ feat, const int* __restrict__ srcs,
    const int* __restrict__ rowptr,
    const float* __restrict__ Wl, const float* __restrict__ bl,
    const float* __restrict__ Wr,
    const float* __restrict__ gam, const float* __restrict__ bet,
    const float* __restrict__ rme, const float* __restrict__ rva,
    float* __restrict__ outf)
{
    __shared__ float sm[8][FD];
    __shared__ float sx[8][FD];
    int t = threadIdx.x;
    int w = t >> 6, lane = t & 63;
    int half = lane >> 5, l5 = lane & 31;
    int node0 = blockIdx.x * 8;
    int nl = 2 * w + half;
    int node = node0 + nl;
    int s0 = rowptr[node], e0 = rowptr[node + 1];
    const float4* f4 = (const float4*)feat;
    float4 a0 = {0,0,0,0}, a1 = {0,0,0,0}, a2 = {0,0,0,0}, a3 = {0,0,0,0};
    int i = s0;
    for (; i + 3 < e0; i += 4) {
        int j0 = srcs[i], j1 = srcs[i + 1], j2 = srcs[i + 2], j3 = srcs[i + 3];
        float4 v0 = f4[(size_t)j0 * 32 + l5];
        float4 v1 = f4[(size_t)j1 * 32 + l5];
        float4 v2 = f4[(size_t)j2 * 32 + l5];
        float4 v3 = f4[(size_t)j3 * 32 + l5];
        a0.x += v0.x; a0.y += v0.y; a0.z += v0.z; a0.w += v0.w;
        a1.x += v1.x; a1.y += v1.y; a1.z += v1.z; a1.w += v1.w;
        a2.x += v2.x; a2.y += v2.y; a2.z += v2.z; a2.w += v2.w;
        a3.x += v3.x; a3.y += v3.y; a3.z += v3.z; a3.w += v3.w;
    }
    for (; i < e0; i++) {
        float4 v = f4[(size_t)srcs[i] * 32 + l5];
        a0.x += v.x; a0.y += v.y; a0.z += v.z; a0.w += v.w;
    }
    float inv = 1.0f / fmaxf((float)(e0 - s0), 1.0f);
    float4 ms;
    ms.x = (a0.x + a1.x + a2.x + a3.x) * inv;
    ms.y = (a0.y + a1.y + a2.y + a3.y) * inv;
    ms.z = (a0.z + a1.z + a2.z + a3.z) * inv;
    ms.w = (a0.w + a1.w + a2.w + a3.w) * inv;
    ((float4*)sm[nl])[l5] = ms;
    ((float4*)sx[nl])[l5] = f4[(size_t)node * 32 + l5];
    __syncthreads();

    int d = t & 127, p = t >> 7;
    const float4* wl4 = (const float4*)(Wl + (size_t)d * FD);
    const float4* wr4 = (const float4*)(Wr + (size_t)d * FD);
    const float4* m0 = (const float4*)sm[4 * p + 0];
    const float4* m1 = (const float4*)sm[4 * p + 1];
    const float4* m2 = (const float4*)sm[4 * p + 2];
    const float4* m3 = (const float4*)sm[4 * p + 3];
    const float4* x0 = (const float4*)sx[4 * p + 0];
    const float4* x1 = (const float4*)sx[4 * p + 1];
    const float4* x2 = (const float4*)sx[4 * p + 2];
    const float4* x3 = (const float4*)sx[4 * p + 3];
    float c0 = 0.f, c1 = 0.f, c2 = 0.f, c3 = 0.f;
    for (int k = 0; k < 32; k++) {
        float4 wl = wl4[k], wr = wr4[k];
        float4 u, v;
        u = m0[k]; v = x0[k];
        c0 += u.x*wl.x + u.y*wl.y + u.z*wl.z + u.w*wl.w
            + v.x*wr.x + v.y*wr.y + v.z*wr.z + v.w*wr.w;
        u = m1[k]; v = x1[k];
        c1 += u.x*wl.x + u.y*wl.y + u.z*wl.z + u.w*wl.w
            + v.x*wr.x + v.y*wr.y + v.z*wr.z + v.w*wr.w;
        u = m2[k]; v = x2[k];
        c2 += u.x*wl.x + u.y*wl.y + u.z*wl.z + u.w*wl.w
            + v.x*wr.x + v.y*wr.y + v.z*wr.z + v.w*wr.w;
        u = m3[k]; v = x3[k];
        c3 += u.x*wl.x + u.y*wl.y + u.z*wl.z + u.w*wl.w
            + v.x*wr.x + v.y*wr.y + v.z*wr.z + v.w*wr.w;
    }
    float bb = bl[d];
    float scale = gam[d] * rsqrtf(rva[d] + 1e-5f);
    float rm = rme[d];
    float bt = bet[d];
    float r0 = fmaxf(scale * (c0 + bb - rm) + bt, 0.f);
    float r1 = fmaxf(scale * (c1 + bb - rm) + bt, 0.f);
    float r2 = fmaxf(scale * (c2 + bb - rm) + bt, 0.f);
    float r3 = fmaxf(scale * (c3 + bb - rm) + bt, 0.f);
    outf[(size_t)(node0 + 4 * p + 0) * FD + d] = r0;
    outf[(size_t)(node0 + 4 * p + 1) * FD + d] = r1;
    outf[(size_t)(node0 + 4 * p + 2) * FD + d] = r2;
    outf[(size_t)(node0 + 4 * p + 3) * FD + d] = r3;
}

// ---- zero-init set2set state ----
__global__ void k_init0(float* __restrict__ qstar, float* __restrict__ hbuf,
                        float* __restrict__ cbuf) {
    int i = blockIdx.x * blockDim.x + threadIdx.x;  // grid 512*256 = 131072
    if (i < NG * 256) qstar[i] = 0.f;
    else if (i < NG * 256 + NG * FD) hbuf[i - NG * 256] = 0.f;
    else cbuf[i - NG * 256 - NG * FD] = 0.f;
}

// ---- gates = qstar @ Wih^T + h @ Whh^T + bih + bhh ; tile [32 graphs x 64 rows] ----
__global__ __launch_bounds__(256) void k_gates(
    const float* __restrict__ qstar, const float* __restrict__ hbuf,
    const float* __restrict__ Wih, const float* __restrict__ Whh,
    const float* __restrict__ bih, const float* __restrict__ bhh,
    float* __restrict__ gates)
{
    __shared__ float X[32][384];
    int t = threadIdx.x;
    int gt = blockIdx.x & 7, rt = blockIdx.x >> 3;
    int G0 = gt * 32, R0 = rt * 64;
    const float4* q4 = (const float4*)qstar;  // [256][64] float4
    const float4* h4 = (const float4*)hbuf;   // [256][32] float4
#pragma unroll
    for (int i = 0; i < 12; i++) {
        int f = i * 256 + t;          // 0..3071
        int g = f / 96, c4 = f % 96;
        float4 v = (c4 < 64) ? q4[(size_t)(G0 + g) * 64 + c4]
                             : h4[(size_t)(G0 + g) * 32 + (c4 - 64)];
        ((float4*)X[g])[c4] = v;
    }
    __syncthreads();
    int r = t & 63, gq = t >> 6;
    int R = R0 + r;
    const float4* wi4 = (const float4*)(Wih + (size_t)R * 256);
    const float4* wh4 = (const float4*)(Whh + (size_t)R * 128);
    float bias = bih[R] + bhh[R];
    float acc[8];
#pragma unroll
    for (int j = 0; j < 8; j++) acc[j] = bias;
    for (int k = 0; k < 64; k++) {
        float4 wv = wi4[k];
#pragma unroll
        for (int j = 0; j < 8; j++) {
            float4 xv = ((const float4*)X[gq + 4 * j])[k];
            acc[j] += xv.x*wv.x + xv.y*wv.y + xv.z*wv.z + xv.w*wv.w;
        }
    }
    for (int k = 0; k < 32; k++) {
        float4 wv = wh4[k];
#pragma unroll
        for (int j = 0; j < 8; j++) {
            float4 xv = ((const float4*)X[gq + 4 * j])[64 + k];
            acc[j] += xv.x*wv.x + xv.y*wv.y + xv.z*wv.z + xv.w*wv.w;
        }
    }
#pragma unroll
    for (int j = 0; j < 8; j++)
        gates[(size_t)(G0 + gq + 4 * j) * 512 + R] = acc[j];
}

// ---- LSTM pointwise: h,c update ----
__global__ __launch_bounds__(256) void k_lstm(const float* __restrict__ gates,
                                              float* __restrict__ hbuf,
                                              float* __restrict__ cbuf) {
    int i = blockIdx.x * 256 + threadIdx.x;  // grid 128 -> 32768
    int g = i >> 7, d = i & 127;
    const float* gr = gates + (size_t)g * 512;
    float ig = gr[d], fg = gr[128 + d], gg = gr[256 + d], og = gr[384 + d];
    float c = sigf(fg) * cbuf[i] + sigf(ig) * tanhf(gg);
    float h = sigf(og) * tanhf(c);
    cbuf[i] = c; hbuf[i] = h;
}

// ---- e[n] = dot(h2[n], h[batch[n]]) ; one wave per node ----
__global__ __launch_bounds__(256) void k_edot(const float* __restrict__ h2,
                                              const float* __restrict__ hbuf,
                                              const int* __restrict__ batch,
                                              float* __restrict__ e) {
    int w = threadIdx.x >> 6, lane = threadIdx.x & 63;
    int n = blockIdx.x * 4 + w;   // grid 10000 -> exactly 40000
    int b = batch[n];
    float2 v = ((const float2*)(h2 + (size_t)n * FD))[lane];
    float2 q = ((const float2*)(hbuf + (size_t)b * FD))[lane];
    float d = v.x * q.x + v.y * q.y;
#pragma unroll
    for (int off = 32; off; off >>= 1) d += __shfl_xor(d, off);
    if (lane == 0) e[n] = d;
}

// ---- per-graph softmax-weighted sum + qstar update ----
__global__ __launch_bounds__(256) void k_attn(
    const float* __restrict__ h2, const float* __restrict__ e,
    const int* __restrict__ gptr, const float* __restrict__ hbuf,
    float* __restrict__ qstar)
{
    int b = blockIdx.x, t = threadIdx.x;
    int wave = t >> 6, lane = t & 63;
    __shared__ float wmax[4], wden[4], red[4][FD];
    int start = gptr[b], end = gptr[b + 1];
    float m = -INFINITY;
    for (int i = start + t; i < end; i += 256) m = fmaxf(m, e[i]);
#pragma unroll
    for (int off = 32; off; off >>= 1) m = fmaxf(m, __shfl_xor(m, off));
    if (lane == 0) wmax[wave] = m;
    __syncthreads();
    float emax = fmaxf(fmaxf(wmax[0], wmax[1]), fmaxf(wmax[2], wmax[3]));
    const float2* h22 = (const float2*)h2;
    float r0x = 0.f, r0y = 0.f, r1x = 0.f, r1y = 0.f, d0 = 0.f, d1 = 0.f;
    int n = start + wave;
    for (; n + 4 < end; n += 8) {
        float a0 = __expf(e[n] - emax);
        float a1 = __expf(e[n + 4] - emax);
        float2 v0 = h22[(size_t)n * 64 + lane];
        float2 v1 = h22[(size_t)(n + 4) * 64 + lane];
        r0x += a0 * v0.x; r0y += a0 * v0.y; d0 += a0;
        r1x += a1 * v1.x; r1y += a1 * v1.y; d1 += a1;
    }
    if (n < end) {
        float a0 = __expf(e[n] - emax);
        float2 v0 = h22[(size_t)n * 64 + lane];
        r0x += a0 * v0.x; r0y += a0 * v0.y; d0 += a0;
    }
    red[wave][2 * lane] = r0x + r1x;
    red[wave][2 * lane + 1] = r0y + r1y;
    if (lane == 0) wden[wave] = d0 + d1;
    __syncthreads();
    if (t < FD) {
        float r = red[0][t] + red[1][t] + red[2][t] + red[3][t];
        float den = wden[0] + wden[1] + wden[2] + wden[3];
        float rn = (den > 0.f) ? r / den : 0.f;
        qstar[(size_t)b * 256 + t] = hbuf[(size_t)b * FD + t];
        qstar[(size_t)b * 256 + 128 + t] = rn;
    }
}

// ---- final projection: out = qstar @ Wp^T + bp ; 2 graphs per block ----
__global__ __launch_bounds__(256) void k_proj(
    const float* __restrict__ qstar, const float* __restrict__ Wp,
    const float* __restrict__ bp, float* __restrict__ out)
{
    __shared__ float qs[2][256];
    int t = threadIdx.x;
    int b0 = blockIdx.x * 2;
    qs[0][t] = qstar[(size_t)b0 * 256 + t];
    qs[1][t] = qstar[(size_t)(b0 + 1) * 256 + t];
    __syncthreads();
    int g = t >> 7, d = t & 127;
    const float4* w4 = (const float4*)(Wp + (size_t)d * 256);
    const float4* q4 = (const float4*)qs[g];
    float acc = bp[d];
    for (int k = 0; k < 64; k++) {
        float4 wv = w4[k], qv = q4[k];
        acc += qv.x*wv.x + qv.y*wv.y + qv.z*wv.z + qv.w*wv.w;
    }
    out[(size_t)(b0 + g) * FD + d] = acc;
}

__global__ void k_zero_out(float* __restrict__ out, int n) {
    int i = blockIdx.x * blockDim.x + threadIdx.x;
    if (i < n) out[i] = 0.f;
}

extern "C" void kernel_launch(void* const* d_in, const int* in_sizes, int n_in,
                              void* d_out, int out_size, void* d_ws, size_t ws_size,
                              hipStream_t stream) {
    const float* x   = (const float*)d_in[0];
    const int*  ei    = (const int*)d_in[1];
    const int*  batch = (const int*)d_in[2];
    const float* W1l = (const float*)d_in[3];
    const float* b1l = (const float*)d_in[4];
    const float* W1r = (const float*)d_in[5];
    const float* g1  = (const float*)d_in[6];
    const float* be1 = (const float*)d_in[7];
    const float* rm1 = (const float*)d_in[8];
    const float* rv1 = (const float*)d_in[9];
    const float* W2l = (const float*)d_in[10];
    const float* b2l = (const float*)d_in[11];
    const float* W2r = (const float*)d_in[12];
    const float* g2  = (const float*)d_in[13];
    const float* be2 = (const float*)d_in[14];
    const float* rm2 = (const float*)d_in[15];
    const float* rv2 = (const float*)d_in[16];
    const float* Wih = (const float*)d_in[17];
    const float* Whh = (const float*)d_in[18];
    const float* bih = (const float*)d_in[19];
    const float* bhh = (const float*)d_in[20];
    const float* Wp  = (const float*)d_in[21];
    const float* bp  = (const float*)d_in[22];
    float* out = (float*)d_out;

    auto al = [](size_t s) { return (s + 255) & ~(size_t)255; };
    size_t off_dcnt = 0;
    size_t off_cur  = off_dcnt + al((size_t)NN * 4);
    size_t off_rp   = off_cur  + al((size_t)NN * 4);
    size_t off_gcnt = off_rp   + al((size_t)(NN + 1) * 4);
    size_t off_gptr = off_gcnt + al((size_t)NG * 4);
    size_t off_srcs = off_gptr + al((size_t)(NG + 1) * 4);
    size_t off_h1   = off_srcs + al((size_t)NE * 4);
    size_t off_h2   = off_h1   + al((size_t)NN * FD * 4);
    size_t off_qs   = off_h2   + al((size_t)NN * FD * 4);
    size_t off_hb   = off_qs   + al((size_t)NG * 256 * 4);
    size_t off_cb   = off_hb   + al((size_t)NG * FD * 4);
    size_t off_gt   = off_cb   + al((size_t)NG * FD * 4);
    size_t off_e    = off_gt   + al((size_t)NG * 512 * 4);
    size_t need     = off_e    + al((size_t)NN * 4);

    if (ws_size < need) {
        k_zero_out<<<(out_size + 255) / 256, 256, 0, stream>>>(out, out_size);
        return;
    }

    char* p = (char*)d_ws;
    int* dcnt    = (int*)(p + off_dcnt);
    int* cursor  = (int*)(p + off_cur);
    int* rowptr  = (int*)(p + off_rp);
    int* gcnt    = (int*)(p + off_gcnt);
    int* gptr    = (int*)(p + off_gptr);
    int* srcs    = (int*)(p + off_srcs);
    float* h1    = (float*)(p + off_h1);
    float* h2    = (float*)(p + off_h2);
    float* qstar = (float*)(p + off_qs);
    float* hbuf  = (float*)(p + off_hb);
    float* cbuf  = (float*)(p + off_cb);
    float* gates = (float*)(p + off_gt);
    float* ebuf  = (float*)(p + off_e);

    hipMemsetAsync(dcnt, 0, (size_t)NN * 4, stream);
    hipMemsetAsync(cursor, 0, (size_t)NN * 4, stream);
    hipMemsetAsync(gcnt, 0, (size_t)NG * 4, stream);

    // CSR build
    k_hist<<<(NE + 255) / 256, 256, 0, stream>>>(ei, batch, dcnt, gcnt);
    k_scan_nodes<<<1, 1024, 0, stream>>>(dcnt, rowptr);
    k_scan<<<1, NG, 0, stream>>>(gcnt, gptr);
    k_permute<<<(NE + 255) / 256, 256, 0, stream>>>(ei, rowptr, cursor, srcs);

    // SAGE layers
    k_combine<<<NN / 8, 256, 0, stream>>>(x, srcs, rowptr, W1l, b1l, W1r, g1, be1, rm1, rv1, h1);
    k_combine<<<NN / 8, 256, 0, stream>>>(h1, srcs, rowptr, W2l, b2l, W2r, g2, be2, rm2, rv2, h2);

    // set2set state init
    k_init0<<<512, 256, 0, stream>>>(qstar, hbuf, cbuf);

    for (int step = 0; step < 3; step++) {
        k_gates<<<64, 256, 0, stream>>>(qstar, hbuf, Wih, Whh, bih, bhh, gates);
        k_lstm<<<128, 256, 0, stream>>>(gates, hbuf, cbuf);
        k_edot<<<NN / 4, 256, 0, stream>>>(h2, hbuf, batch, ebuf);
        k_attn<<<NG, 256, 0, stream>>>(h2, ebuf, gptr, hbuf, qstar);
    }
    k_proj<<<NG / 2, 256, 0, stream>>>(qstar, Wp, bp, out);
}

// Round 6
// 652.570 us; speedup vs baseline: 2.9768x; 1.2125x over previous
//
#include <hip/hip_runtime.h>
#include <hip/hip_bf16.h>
#include <math.h>

#define NN 40000
#define NE 640000
#define NG 256
#define FD 128

__device__ __forceinline__ float sigf(float x) { return 1.f / (1.f + __expf(-x)); }

// ---- degree histogram per dst node + nodes-per-graph histogram ----
__global__ void k_hist(const int* __restrict__ ei, const int* __restrict__ batch,
                       int* __restrict__ dcnt, int* __restrict__ gcnt) {
    int i = blockIdx.x * blockDim.x + threadIdx.x;
    if (i < NE) atomicAdd(&dcnt[ei[NE + i]], 1);
    if (i < NN) atomicAdd(&gcnt[batch[i]], 1);
}

// ---- exclusive scan of 40000 node degrees -> rowptr[NN+1]; 1 block, 1024 thr ----
#define SCH 40  // 1024 * 40 = 40960 >= NN
__global__ __launch_bounds__(1024) void k_scan_nodes(const int* __restrict__ dcnt,
                                                     int* __restrict__ rowptr) {
    __shared__ int s[1024];
    int t = threadIdx.x;
    int base = t * SCH;
    int local = 0;
#pragma unroll
    for (int i = 0; i < SCH; i++) {
        int idx = base + i;
        if (idx < NN) local += dcnt[idx];
    }
    s[t] = local;
    __syncthreads();
    for (int off = 1; off < 1024; off <<= 1) {
        int v = (t >= off) ? s[t - off] : 0;
        __syncthreads();
        s[t] += v;
        __syncthreads();
    }
    int run = s[t] - local;  // exclusive prefix
#pragma unroll
    for (int i = 0; i < SCH; i++) {
        int idx = base + i;
        if (idx < NN) { rowptr[idx] = run; run += dcnt[idx]; }
    }
    if (t == 0) rowptr[NN] = s[1023];
}

// ---- exclusive scan of 256 graph counts -> gptr[257] (batch is sorted) ----
__global__ void k_scan(const int* __restrict__ gcnt, int* __restrict__ gptr) {
    __shared__ int s[NG];
    int t = threadIdx.x;
    s[t] = gcnt[t];
    __syncthreads();
    for (int off = 1; off < NG; off <<= 1) {
        int v = (t >= off) ? s[t - off] : 0;
        __syncthreads();
        s[t] += v;
        __syncthreads();
    }
    gptr[t + 1] = s[t];
    if (t == 0) gptr[0] = 0;
}

// ---- bucket edge sources by dst: srcs[rowptr[dst]...] = src ----
__global__ void k_permute(const int* __restrict__ ei, const int* __restrict__ rowptr,
                          int* __restrict__ cursor, int* __restrict__ srcs) {
    int i = blockIdx.x * blockDim.x + threadIdx.x;
    if (i >= NE) return;
    int dst = ei[NE + i];
    int pos = atomicAdd(&cursor[dst], 1);
    srcs[rowptr[dst] + pos] = ei[i];
}

// ---- dense transform: Y[n][0:128] = in_n @ Wl^T ; Y[n][128:256] = in_n @ Wr^T ----
// 32 nodes per block, 256 threads; thread t owns ONE output column:
//   t < 128 -> Wl column t ; t >= 128 -> Wr column t-128.  (FIX for round 5:
//   previous version had threads 128..255 reading OOB weight rows and writing
//   past the 256-wide Y row.)
// In-place safe for in == &Y[.][128] with instride4==64: each block stages its
// own 32 rows into LDS before writing those same rows.
__global__ __launch_bounds__(256) void k_xform(
    const float* __restrict__ in, int instride4,
    const float* __restrict__ Wl, const float* __restrict__ Wr,
    float* __restrict__ Y)
{
    __shared__ float4 Xs[32 * 32];  // [row][k4]
    int t = threadIdx.x;
    int node0 = blockIdx.x * 32;
    const float4* in4 = (const float4*)in;
#pragma unroll
    for (int i = 0; i < 4; i++) {
        int f = t + i * 256;            // 0..1023
        int row = f >> 5, c4 = f & 31;
        Xs[f] = in4[(size_t)(node0 + row) * instride4 + c4];
    }
    __syncthreads();
    const float* Wsel = (t < 128) ? Wl : Wr;
    const float4* w4 = (const float4*)(Wsel + (size_t)(t & 127) * FD);
    float acc[32];
#pragma unroll
    for (int r = 0; r < 32; r++) acc[r] = 0.f;
    for (int k4 = 0; k4 < 32; k4++) {
        float4 w = w4[k4];
#pragma unroll
        for (int r = 0; r < 32; r++) {
            float4 xv = Xs[r * 32 + k4];       // broadcast across all threads
            acc[r] += xv.x*w.x + xv.y*w.y + xv.z*w.z + xv.w*w.w;
        }
    }
#pragma unroll
    for (int r = 0; r < 32; r++)
        Y[(size_t)(node0 + r) * 256 + t] = acc[r];
}

// ---- pure gather: h[n] = ReLU(scale*(mean_j Yl[j] + bl + Yr[n] - rm) + bt) ----
// One node per half-wave (32 lanes x float4), 8 nodes per 256-thr block.
// Writes h in-place into the RIGHT half of Y (no other node reads right halves).
__global__ __launch_bounds__(256) void k_gather(
    float* __restrict__ Y, const int* __restrict__ srcs,
    const int* __restrict__ rowptr,
    const float* __restrict__ bl,
    const float* __restrict__ gam, const float* __restrict__ bet,
    const float* __restrict__ rme, const float* __restrict__ rva)
{
    int t = threadIdx.x;
    int hw = t >> 5, l5 = t & 31;
    int node = blockIdx.x * 8 + hw;
    int s0 = rowptr[node], e0 = rowptr[node + 1];
    const float4* Y4 = (const float4*)Y;   // row stride 64 float4
    float4 a0 = {0,0,0,0}, a1 = {0,0,0,0}, a2 = {0,0,0,0}, a3 = {0,0,0,0};
    float4 a4 = {0,0,0,0}, a5 = {0,0,0,0}, a6 = {0,0,0,0}, a7 = {0,0,0,0};
    int i = s0;
    for (; i + 7 < e0; i += 8) {
        int j0 = srcs[i], j1 = srcs[i+1], j2 = srcs[i+2], j3 = srcs[i+3];
        int j4 = srcs[i+4], j5 = srcs[i+5], j6 = srcs[i+6], j7 = srcs[i+7];
        float4 v0 = Y4[(size_t)j0 * 64 + l5];
        float4 v1 = Y4[(size_t)j1 * 64 + l5];
        float4 v2 = Y4[(size_t)j2 * 64 + l5];
        float4 v3 = Y4[(size_t)j3 * 64 + l5];
        float4 v4 = Y4[(size_t)j4 * 64 + l5];
        float4 v5 = Y4[(size_t)j5 * 64 + l5];
        float4 v6 = Y4[(size_t)j6 * 64 + l5];
        float4 v7 = Y4[(size_t)j7 * 64 + l5];
        a0.x += v0.x; a0.y += v0.y; a0.z += v0.z; a0.w += v0.w;
        a1.x += v1.x; a1.y += v1.y; a1.z += v1.z; a1.w += v1.w;
        a2.x += v2.x; a2.y += v2.y; a2.z += v2.z; a2.w += v2.w;
        a3.x += v3.x; a3.y += v3.y; a3.z += v3.z; a3.w += v3.w;
        a4.x += v4.x; a4.y += v4.y; a4.z += v4.z; a4.w += v4.w;
        a5.x += v5.x; a5.y += v5.y; a5.z += v5.z; a5.w += v5.w;
        a6.x += v6.x; a6.y += v6.y; a6.z += v6.z; a6.w += v6.w;
        a7.x += v7.x; a7.y += v7.y; a7.z += v7.z; a7.w += v7.w;
    }
    for (; i < e0; i++) {
        float4 v = Y4[(size_t)srcs[i] * 64 + l5];
        a0.x += v.x; a0.y += v.y; a0.z += v.z; a0.w += v.w;
    }
    float inv = 1.0f / fmaxf((float)(e0 - s0), 1.0f);
    float4 m;
    m.x = (a0.x + a1.x + a2.x + a3.x + a4.x + a5.x + a6.x + a7.x) * inv;
    m.y = (a0.y + a1.y + a2.y + a3.y + a4.y + a5.y + a6.y + a7.y) * inv;
    m.z = (a0.z + a1.z + a2.z + a3.z + a4.z + a5.z + a6.z + a7.z) * inv;
    m.w = (a0.w + a1.w + a2.w + a3.w + a4.w + a5.w + a6.w + a7.w) * inv;
    float4 yr = Y4[(size_t)node * 64 + 32 + l5];
    float4 g4 = ((const float4*)gam)[l5];
    float4 rv4 = ((const float4*)rva)[l5];
    float4 rm4 = ((const float4*)rme)[l5];
    float4 bt4 = ((const float4*)bet)[l5];
    float4 bb4 = ((const float4*)bl)[l5];
    float4 z;
    float sx = g4.x * rsqrtf(rv4.x + 1e-5f);
    float sy = g4.y * rsqrtf(rv4.y + 1e-5f);
    float sz = g4.z * rsqrtf(rv4.z + 1e-5f);
    float sw = g4.w * rsqrtf(rv4.w + 1e-5f);
    z.x = fmaxf(sx * (m.x + yr.x + bb4.x - rm4.x) + bt4.x, 0.f);
    z.y = fmaxf(sy * (m.y + yr.y + bb4.y - rm4.y) + bt4.y, 0.f);
    z.z = fmaxf(sz * (m.z + yr.z + bb4.z - rm4.z) + bt4.z, 0.f);
    z.w = fmaxf(sw * (m.w + yr.w + bb4.w - rm4.w) + bt4.w, 0.f);
    ((float4*)Y)[(size_t)node * 64 + 32 + l5] = z;
}

// ---- zero-init set2set state ----
__global__ void k_init0(float* __restrict__ qstar, float* __restrict__ hbuf,
                        float* __restrict__ cbuf) {
    int i = blockIdx.x * blockDim.x + threadIdx.x;  // grid 512*256 = 131072
    if (i < NG * 256) qstar[i] = 0.f;
    else if (i < NG * 256 + NG * FD) hbuf[i - NG * 256] = 0.f;
    else cbuf[i - NG * 256 - NG * FD] = 0.f;
}

// ---- gates = qstar @ Wih^T + h @ Whh^T + bih + bhh ; tile [32 graphs x 64 rows] ----
__global__ __launch_bounds__(256) void k_gates(
    const float* __restrict__ qstar, const float* __restrict__ hbuf,
    const float* __restrict__ Wih, const float* __restrict__ Whh,
    const float* __restrict__ bih, const float* __restrict__ bhh,
    float* __restrict__ gates)
{
    __shared__ float X[32][384];
    int t = threadIdx.x;
    int gt = blockIdx.x & 7, rt = blockIdx.x >> 3;
    int G0 = gt * 32, R0 = rt * 64;
    const float4* q4 = (const float4*)qstar;  // [256][64] float4
    const float4* h4 = (const float4*)hbuf;   // [256][32] float4
#pragma unroll
    for (int i = 0; i < 12; i++) {
        int f = i * 256 + t;          // 0..3071
        int g = f / 96, c4 = f % 96;
        float4 v = (c4 < 64) ? q4[(size_t)(G0 + g) * 64 + c4]
                             : h4[(size_t)(G0 + g) * 32 + (c4 - 64)];
        ((float4*)X[g])[c4] = v;
    }
    __syncthreads();
    int r = t & 63, gq = t >> 6;
    int R = R0 + r;
    const float4* wi4 = (const float4*)(Wih + (size_t)R * 256);
    const float4* wh4 = (const float4*)(Whh + (size_t)R * 128);
    float bias = bih[R] + bhh[R];
    float acc[8];
#pragma unroll
    for (int j = 0; j < 8; j++) acc[j] = bias;
    for (int k = 0; k < 64; k++) {
        float4 wv = wi4[k];
#pragma unroll
        for (int j = 0; j < 8; j++) {
            float4 xv = ((const float4*)X[gq + 4 * j])[k];
            acc[j] += xv.x*wv.x + xv.y*wv.y + xv.z*wv.z + xv.w*wv.w;
        }
    }
    for (int k = 0; k < 32; k++) {
        float4 wv = wh4[k];
#pragma unroll
        for (int j = 0; j < 8; j++) {
            float4 xv = ((const float4*)X[gq + 4 * j])[64 + k];
            acc[j] += xv.x*wv.x + xv.y*wv.y + xv.z*wv.z + xv.w*wv.w;
        }
    }
#pragma unroll
    for (int j = 0; j < 8; j++)
        gates[(size_t)(G0 + gq + 4 * j) * 512 + R] = acc[j];
}

// ---- fused LSTM pointwise + online-softmax attention + qstar update ----
// One block (256 thr) per graph. h2 row n lives at Y + n*256 + 128.
__global__ __launch_bounds__(256) void k_attn2(
    const float* __restrict__ Y, const float* __restrict__ gates,
    const int* __restrict__ gptr,
    float* __restrict__ hbuf, float* __restrict__ cbuf,
    float* __restrict__ qstar)
{
    int b = blockIdx.x, t = threadIdx.x;
    int wave = t >> 6, lane = t & 63;
    __shared__ float hs[FD];
    __shared__ float wm[4], wd[4], red[4][FD];

    if (t < FD) {
        const float* gr = gates + (size_t)b * 512;
        float ig = gr[t], fg = gr[FD + t], gg = gr[2 * FD + t], og = gr[3 * FD + t];
        float c = sigf(fg) * cbuf[(size_t)b * FD + t] + sigf(ig) * tanhf(gg);
        float h = sigf(og) * tanhf(c);
        cbuf[(size_t)b * FD + t] = c;
        hbuf[(size_t)b * FD + t] = h;
        hs[t] = h;
    }
    __syncthreads();

    int start = gptr[b], end = gptr[b + 1];
    float2 q = ((const float2*)hs)[lane];
    const float2* Y2 = (const float2*)Y;   // row stride 128 float2; h2 at +64
    float mw = -INFINITY, dw = 0.f, rx = 0.f, ry = 0.f;
    for (int n = start + wave; n < end; n += 4) {
        float2 v = Y2[(size_t)n * 128 + 64 + lane];
        float e = v.x * q.x + v.y * q.y;
#pragma unroll
        for (int off = 32; off; off >>= 1) e += __shfl_xor(e, off);
        float mn = fmaxf(mw, e);
        float corr = __expf(mw - mn);     // first iter: exp(-inf)=0
        float a = __expf(e - mn);
        rx = rx * corr + a * v.x;
        ry = ry * corr + a * v.y;
        dw = dw * corr + a;
        mw = mn;
    }
    if (lane == 0) wm[wave] = mw;
    __syncthreads();
    float M = fmaxf(fmaxf(wm[0], wm[1]), fmaxf(wm[2], wm[3]));
    float cr = (M == -INFINITY) ? 0.f : __expf(mw - M);
    red[wave][2 * lane] = rx * cr;
    red[wave][2 * lane + 1] = ry * cr;
    if (lane == 0) wd[wave] = dw * cr;
    __syncthreads();
    if (t < FD) {
        float r = red[0][t] + red[1][t] + red[2][t] + red[3][t];
        float den = wd[0] + wd[1] + wd[2] + wd[3];
        float rn = (den > 0.f) ? r / den : 0.f;
        qstar[(size_t)b * 256 + t] = hs[t];
        qstar[(size_t)b * 256 + FD + t] = rn;
    }
}

// ---- final projection: out = qstar @ Wp^T + bp ; 2 graphs per block ----
__global__ __launch_bounds__(256) void k_proj(
    const float* __restrict__ qstar, const float* __restrict__ Wp,
    const float* __restrict__ bp, float* __restrict__ out)
{
    __shared__ float qs[2][256];
    int t = threadIdx.x;
    int b0 = blockIdx.x * 2;
    qs[0][t] = qstar[(size_t)b0 * 256 + t];
    qs[1][t] = qstar[(size_t)(b0 + 1) * 256 + t];
    __syncthreads();
    int g = t >> 7, d = t & 127;
    const float4* w4 = (const float4*)(Wp + (size_t)d * 256);
    const float4* q4 = (const float4*)qs[g];
    float acc = bp[d];
    for (int k = 0; k < 64; k++) {
        float4 wv = w4[k], qv = q4[k];
        acc += qv.x*wv.x + qv.y*wv.y + qv.z*wv.z + qv.w*wv.w;
    }
    out[(size_t)(b0 + g) * FD + d] = acc;
}

__global__ void k_zero_out(float* __restrict__ out, int n) {
    int i = blockIdx.x * blockDim.x + threadIdx.x;
    if (i < n) out[i] = 0.f;
}

extern "C" void kernel_launch(void* const* d_in, const int* in_sizes, int n_in,
                              void* d_out, int out_size, void* d_ws, size_t ws_size,
                              hipStream_t stream) {
    const float* x   = (const float*)d_in[0];
    const int*  ei    = (const int*)d_in[1];
    const int*  batch = (const int*)d_in[2];
    const float* W1l = (const float*)d_in[3];
    const float* b1l = (const float*)d_in[4];
    const float* W1r = (const float*)d_in[5];
    const float* g1  = (const float*)d_in[6];
    const float* be1 = (const float*)d_in[7];
    const float* rm1 = (const float*)d_in[8];
    const float* rv1 = (const float*)d_in[9];
    const float* W2l = (const float*)d_in[10];
    const float* b2l = (const float*)d_in[11];
    const float* W2r = (const float*)d_in[12];
    const float* g2  = (const float*)d_in[13];
    const float* be2 = (const float*)d_in[14];
    const float* rm2 = (const float*)d_in[15];
    const float* rv2 = (const float*)d_in[16];
    const float* Wih = (const float*)d_in[17];
    const float* Whh = (const float*)d_in[18];
    const float* bih = (const float*)d_in[19];
    const float* bhh = (const float*)d_in[20];
    const float* Wp  = (const float*)d_in[21];
    const float* bp  = (const float*)d_in[22];
    float* out = (float*)d_out;

    auto al = [](size_t s) { return (s + 255) & ~(size_t)255; };
    size_t off_dcnt = 0;
    size_t off_cur  = off_dcnt + al((size_t)NN * 4);
    size_t off_gcnt = off_cur  + al((size_t)NN * 4);
    size_t off_gptr = off_gcnt + al((size_t)NG * 4);
    size_t off_rp   = off_gptr + al((size_t)(NG + 1) * 4);
    size_t off_srcs = off_rp   + al((size_t)(NN + 1) * 4);
    size_t off_Y    = off_srcs + al((size_t)NE * 4);
    size_t off_qs   = off_Y    + al((size_t)NN * 256 * 4);
    size_t off_hb   = off_qs   + al((size_t)NG * 256 * 4);
    size_t off_cb   = off_hb   + al((size_t)NG * FD * 4);
    size_t off_gt   = off_cb   + al((size_t)NG * FD * 4);
    size_t need     = off_gt   + al((size_t)NG * 512 * 4);

    if (ws_size < need) {
        k_zero_out<<<(out_size + 255) / 256, 256, 0, stream>>>(out, out_size);
        return;
    }

    char* p = (char*)d_ws;
    int* dcnt    = (int*)(p + off_dcnt);
    int* cursor  = (int*)(p + off_cur);
    int* gcnt    = (int*)(p + off_gcnt);
    int* gptr    = (int*)(p + off_gptr);
    int* rowptr  = (int*)(p + off_rp);
    int* srcs    = (int*)(p + off_srcs);
    float* Y     = (float*)(p + off_Y);
    float* qstar = (float*)(p + off_qs);
    float* hbuf  = (float*)(p + off_hb);
    float* cbuf  = (float*)(p + off_cb);
    float* gates = (float*)(p + off_gt);

    // one memset covers dcnt + cursor + gcnt (contiguous)
    hipMemsetAsync(p, 0, off_gptr, stream);

    // CSR build
    k_hist<<<(NE + 255) / 256, 256, 0, stream>>>(ei, batch, dcnt, gcnt);
    k_scan_nodes<<<1, 1024, 0, stream>>>(dcnt, rowptr);
    k_scan<<<1, NG, 0, stream>>>(gcnt, gptr);
    k_permute<<<(NE + 255) / 256, 256, 0, stream>>>(ei, rowptr, cursor, srcs);

    // layer 1: x -> Y (transform), then gather -> h1 (into right half of Y)
    k_xform<<<NN / 32, 256, 0, stream>>>(x, 32, W1l, W1r, Y);
    k_gather<<<NN / 8, 256, 0, stream>>>(Y, srcs, rowptr, b1l, g1, be1, rm1, rv1);

    // layer 2: h1 (right half of Y) -> Y (in-place transform), gather -> h2
    k_xform<<<NN / 32, 256, 0, stream>>>(Y + 128, 64, W2l, W2r, Y);
    k_gather<<<NN / 8, 256, 0, stream>>>(Y, srcs, rowptr, b2l, g2, be2, rm2, rv2);

    // set2set state init
    k_init0<<<512, 256, 0, stream>>>(qstar, hbuf, cbuf);

    for (int step = 0; step < 3; step++) {
        k_gates<<<64, 256, 0, stream>>>(qstar, hbuf, Wih, Whh, bih, bhh, gates);
        k_attn2<<<NG, 256, 0, stream>>>(Y, gates, gptr, hbuf, cbuf, qstar);
    }
    k_proj<<<NG / 2, 256, 0, stream>>>(qstar, Wp, bp, out);
}

// Round 7
// 501.748 us; speedup vs baseline: 3.8716x; 1.3006x over previous
//
#include <hip/hip_runtime.h>
#include <hip/hip_bf16.h>
#include <math.h>

#define NN 40000
#define NE 640000
#define NG 256
#define FD 128

typedef __attribute__((ext_vector_type(8))) short bf16x8;
typedef __attribute__((ext_vector_type(4))) float f32x4;

__device__ __forceinline__ float sigf(float x) { return 1.f / (1.f + __expf(-x)); }
__device__ __forceinline__ unsigned short f2b(float f) {
    unsigned int u = __float_as_uint(f);
    return (unsigned short)((u + 0x7FFFu + ((u >> 16) & 1u)) >> 16);
}
__device__ __forceinline__ float b2f(unsigned int u16) {
    return __uint_as_float(u16 << 16);
}

// ---- degree histogram per dst node + nodes-per-graph histogram ----
__global__ void k_hist(const int* __restrict__ ei, const int* __restrict__ batch,
                       int* __restrict__ dcnt, int* __restrict__ gcnt) {
    int i = blockIdx.x * blockDim.x + threadIdx.x;
    if (i < NE) atomicAdd(&dcnt[ei[NE + i]], 1);
    if (i < NN) atomicAdd(&gcnt[batch[i]], 1);
}

// ---- exclusive scan of 40000 node degrees -> rowptr[NN+1]; 1 block, 1024 thr ----
#define SCH 40  // 1024 * 40 = 40960 >= NN
__global__ __launch_bounds__(1024) void k_scan_nodes(const int* __restrict__ dcnt,
                                                     int* __restrict__ rowptr) {
    __shared__ int s[1024];
    int t = threadIdx.x;
    int base = t * SCH;
    int local = 0;
#pragma unroll
    for (int i = 0; i < SCH; i++) {
        int idx = base + i;
        if (idx < NN) local += dcnt[idx];
    }
    s[t] = local;
    __syncthreads();
    for (int off = 1; off < 1024; off <<= 1) {
        int v = (t >= off) ? s[t - off] : 0;
        __syncthreads();
        s[t] += v;
        __syncthreads();
    }
    int run = s[t] - local;  // exclusive prefix
#pragma unroll
    for (int i = 0; i < SCH; i++) {
        int idx = base + i;
        if (idx < NN) { rowptr[idx] = run; run += dcnt[idx]; }
    }
    if (t == 0) rowptr[NN] = s[1023];
}

// ---- exclusive scan of 256 graph counts -> gptr[257] (batch is sorted) ----
__global__ void k_scan(const int* __restrict__ gcnt, int* __restrict__ gptr) {
    __shared__ int s[NG];
    int t = threadIdx.x;
    s[t] = gcnt[t];
    __syncthreads();
    for (int off = 1; off < NG; off <<= 1) {
        int v = (t >= off) ? s[t - off] : 0;
        __syncthreads();
        s[t] += v;
        __syncthreads();
    }
    gptr[t + 1] = s[t];
    if (t == 0) gptr[0] = 0;
}

// ---- bucket edge sources by dst: srcs[rowptr[dst]...] = src ----
__global__ void k_permute(const int* __restrict__ ei, const int* __restrict__ rowptr,
                          int* __restrict__ cursor, int* __restrict__ srcs) {
    int i = blockIdx.x * blockDim.x + threadIdx.x;
    if (i >= NE) return;
    int dst = ei[NE + i];
    int pos = atomicAdd(&cursor[dst], 1);
    srcs[rowptr[dst] + pos] = ei[i];
}

// ---- fp32 -> bf16 conversions ----
__global__ void k_cvt_x(const float* __restrict__ in, unsigned short* __restrict__ out) {
    int i = (blockIdx.x * 256 + threadIdx.x) * 4;  // grid 5000 -> 5,120,000
    float4 v = *(const float4*)(in + i);
    ushort4 o;
    o.x = f2b(v.x); o.y = f2b(v.y); o.z = f2b(v.z); o.w = f2b(v.w);
    *(ushort4*)(out + i) = o;
}
// Wb[0:128] = Wl, Wb[128:256] = Wr (each 128x128), bf16
__global__ void k_cvt_w(const float* __restrict__ Wl, const float* __restrict__ Wr,
                        unsigned short* __restrict__ Wb) {
    int i = blockIdx.x * 256 + threadIdx.x;   // grid 128 -> 32768
    Wb[i] = f2b(i < 16384 ? Wl[i] : Wr[i - 16384]);
}

// ---- MFMA GEMM: C[n][0:256] = A[n][0:128] @ Wb^T  (A,W,C all bf16) ----
// Block: 256 thr (4 waves), 64 A-rows; W fully staged in LDS (64 KB, XOR-swizzled).
// mfma_f32_16x16x32_bf16 layouts (doc-verified): A: m=lane&15, k=quad*8+j;
// B: n=lane&15, k=quad*8+j (our W is [n][k] row-major -> direct);
// D: col(n)=lane&15, row(m)=quad*4+reg.
__global__ __launch_bounds__(256) void k_mm(
    const unsigned short* __restrict__ A,   // [NN][128] bf16
    const unsigned short* __restrict__ W,   // [256][128] bf16
    unsigned short* __restrict__ C)         // [NN][256] bf16
{
    __shared__ unsigned short Ws[256 * 128];   // 64 KB
    int t = threadIdx.x;
    {
        const uint4* Wg = (const uint4*)W;     // 4096 x 16B, 16 per row
#pragma unroll
        for (int i = 0; i < 16; i++) {
            int f = i * 256 + t;
            int row = f >> 4, c = f & 15;
            int cs = c ^ (row & 15);           // XOR swizzle on 16B chunks
            *(uint4*)&Ws[row * 128 + cs * 8] = Wg[f];
        }
    }
    __syncthreads();
    int w = t >> 6, lane = t & 63;
    int ln = lane & 15, quad = lane >> 4;
    int m0 = blockIdx.x * 64 + w * 16;
    bf16x8 a[4];
    const unsigned short* Arow = A + (size_t)(m0 + ln) * 128;
#pragma unroll
    for (int ks = 0; ks < 4; ks++)
        a[ks] = *(const bf16x8*)(Arow + ks * 32 + quad * 8);
    for (int nt = 0; nt < 16; nt++) {
        int n0 = nt * 16;
        int row = n0 + ln;
        f32x4 acc = {0.f, 0.f, 0.f, 0.f};
#pragma unroll
        for (int ks = 0; ks < 4; ks++) {
            int c = ks * 4 + quad;
            bf16x8 b = *(const bf16x8*)&Ws[row * 128 + (c ^ (row & 15)) * 8];
            acc = __builtin_amdgcn_mfma_f32_16x16x32_bf16(a[ks], b, acc, 0, 0, 0);
        }
        size_t base = (size_t)(m0 + quad * 4) * 256 + n0 + ln;
#pragma unroll
        for (int r = 0; r < 4; r++)
            C[base + (size_t)r * 256] = f2b(acc[r]);
    }
}

// ---- gather + BN + ReLU: H[n] = relu(scale*(mean_j C[j][0:128] + bl + C[n][128:256] - rm) + bt) ----
// One node per half-wave; lane covers 4 dims via uint2 (4 bf16). fp32 accumulate.
__global__ __launch_bounds__(256) void k_gather2(
    const unsigned short* __restrict__ C, const int* __restrict__ srcs,
    const int* __restrict__ rowptr,
    const float* __restrict__ bl,
    const float* __restrict__ gam, const float* __restrict__ bet,
    const float* __restrict__ rme, const float* __restrict__ rva,
    unsigned short* __restrict__ H)
{
    int t = threadIdx.x;
    int hw = t >> 5, l5 = t & 31;
    int node = blockIdx.x * 8 + hw;
    int s0 = rowptr[node], e0 = rowptr[node + 1];
    const uint2* C2 = (const uint2*)C;   // row = 64 uint2 (256 bf16)
    float a0 = 0.f, a1 = 0.f, a2 = 0.f, a3 = 0.f;
    int i = s0;
    for (; i + 7 < e0; i += 8) {
        uint2 v0 = C2[(size_t)srcs[i]     * 64 + l5];
        uint2 v1 = C2[(size_t)srcs[i + 1] * 64 + l5];
        uint2 v2 = C2[(size_t)srcs[i + 2] * 64 + l5];
        uint2 v3 = C2[(size_t)srcs[i + 3] * 64 + l5];
        uint2 v4 = C2[(size_t)srcs[i + 4] * 64 + l5];
        uint2 v5 = C2[(size_t)srcs[i + 5] * 64 + l5];
        uint2 v6 = C2[(size_t)srcs[i + 6] * 64 + l5];
        uint2 v7 = C2[(size_t)srcs[i + 7] * 64 + l5];
        a0 += b2f(v0.x & 0xFFFFu) + b2f(v1.x & 0xFFFFu) + b2f(v2.x & 0xFFFFu) + b2f(v3.x & 0xFFFFu)
            + b2f(v4.x & 0xFFFFu) + b2f(v5.x & 0xFFFFu) + b2f(v6.x & 0xFFFFu) + b2f(v7.x & 0xFFFFu);
        a1 += b2f(v0.x >> 16) + b2f(v1.x >> 16) + b2f(v2.x >> 16) + b2f(v3.x >> 16)
            + b2f(v4.x >> 16) + b2f(v5.x >> 16) + b2f(v6.x >> 16) + b2f(v7.x >> 16);
        a2 += b2f(v0.y & 0xFFFFu) + b2f(v1.y & 0xFFFFu) + b2f(v2.y & 0xFFFFu) + b2f(v3.y & 0xFFFFu)
            + b2f(v4.y & 0xFFFFu) + b2f(v5.y & 0xFFFFu) + b2f(v6.y & 0xFFFFu) + b2f(v7.y & 0xFFFFu);
        a3 += b2f(v0.y >> 16) + b2f(v1.y >> 16) + b2f(v2.y >> 16) + b2f(v3.y >> 16)
            + b2f(v4.y >> 16) + b2f(v5.y >> 16) + b2f(v6.y >> 16) + b2f(v7.y >> 16);
    }
    for (; i < e0; i++) {
        uint2 v = C2[(size_t)srcs[i] * 64 + l5];
        a0 += b2f(v.x & 0xFFFFu); a1 += b2f(v.x >> 16);
        a2 += b2f(v.y & 0xFFFFu); a3 += b2f(v.y >> 16);
    }
    float inv = 1.0f / fmaxf((float)(e0 - s0), 1.0f);
    uint2 yr = C2[(size_t)node * 64 + 32 + l5];
    float y0 = a0 * inv + b2f(yr.x & 0xFFFFu);
    float y1 = a1 * inv + b2f(yr.x >> 16);
    float y2 = a2 * inv + b2f(yr.y & 0xFFFFu);
    float y3 = a3 * inv + b2f(yr.y >> 16);
    float4 g4  = ((const float4*)gam)[l5];
    float4 rv4 = ((const float4*)rva)[l5];
    float4 rm4 = ((const float4*)rme)[l5];
    float4 bt4 = ((const float4*)bet)[l5];
    float4 bb4 = ((const float4*)bl)[l5];
    float z0 = fmaxf(g4.x * rsqrtf(rv4.x + 1e-5f) * (y0 + bb4.x - rm4.x) + bt4.x, 0.f);
    float z1 = fmaxf(g4.y * rsqrtf(rv4.y + 1e-5f) * (y1 + bb4.y - rm4.y) + bt4.y, 0.f);
    float z2 = fmaxf(g4.z * rsqrtf(rv4.z + 1e-5f) * (y2 + bb4.z - rm4.z) + bt4.z, 0.f);
    float z3 = fmaxf(g4.w * rsqrtf(rv4.w + 1e-5f) * (y3 + bb4.w - rm4.w) + bt4.w, 0.f);
    ushort4 o;
    o.x = f2b(z0); o.y = f2b(z1); o.z = f2b(z2); o.w = f2b(z3);
    *(ushort4*)(H + (size_t)node * 128 + l5 * 4) = o;
}

// ---- zero-init set2set state ----
__global__ void k_init0(float* __restrict__ qstar, float* __restrict__ hbuf,
                        float* __restrict__ cbuf) {
    int i = blockIdx.x * blockDim.x + threadIdx.x;  // grid 512*256 = 131072
    if (i < NG * 256) qstar[i] = 0.f;
    else if (i < NG * 256 + NG * FD) hbuf[i - NG * 256] = 0.f;
    else cbuf[i - NG * 256 - NG * FD] = 0.f;
}

// ---- gates = qstar @ Wih^T + h @ Whh^T + bih + bhh ; tile [32 graphs x 64 rows] ----
__global__ __launch_bounds__(256) void k_gates(
    const float* __restrict__ qstar, const float* __restrict__ hbuf,
    const float* __restrict__ Wih, const float* __restrict__ Whh,
    const float* __restrict__ bih, const float* __restrict__ bhh,
    float* __restrict__ gates)
{
    __shared__ float X[32][384];
    int t = threadIdx.x;
    int gt = blockIdx.x & 7, rt = blockIdx.x >> 3;
    int G0 = gt * 32, R0 = rt * 64;
    const float4* q4 = (const float4*)qstar;  // [256][64] float4
    const float4* h4 = (const float4*)hbuf;   // [256][32] float4
#pragma unroll
    for (int i = 0; i < 12; i++) {
        int f = i * 256 + t;          // 0..3071
        int g = f / 96, c4 = f % 96;
        float4 v = (c4 < 64) ? q4[(size_t)(G0 + g) * 64 + c4]
                             : h4[(size_t)(G0 + g) * 32 + (c4 - 64)];
        ((float4*)X[g])[c4] = v;
    }
    __syncthreads();
    int r = t & 63, gq = t >> 6;
    int R = R0 + r;
    const float4* wi4 = (const float4*)(Wih + (size_t)R * 256);
    const float4* wh4 = (const float4*)(Whh + (size_t)R * 128);
    float bias = bih[R] + bhh[R];
    float acc[8];
#pragma unroll
    for (int j = 0; j < 8; j++) acc[j] = bias;
    for (int k = 0; k < 64; k++) {
        float4 wv = wi4[k];
#pragma unroll
        for (int j = 0; j < 8; j++) {
            float4 xv = ((const float4*)X[gq + 4 * j])[k];
            acc[j] += xv.x*wv.x + xv.y*wv.y + xv.z*wv.z + xv.w*wv.w;
        }
    }
    for (int k = 0; k < 32; k++) {
        float4 wv = wh4[k];
#pragma unroll
        for (int j = 0; j < 8; j++) {
            float4 xv = ((const float4*)X[gq + 4 * j])[64 + k];
            acc[j] += xv.x*wv.x + xv.y*wv.y + xv.z*wv.z + xv.w*wv.w;
        }
    }
#pragma unroll
    for (int j = 0; j < 8; j++)
        gates[(size_t)(G0 + gq + 4 * j) * 512 + R] = acc[j];
}

// ---- fused LSTM pointwise + online-softmax attention + qstar update ----
// One block (256 thr) per graph. h2 is bf16 [NN][128].
__global__ __launch_bounds__(256) void k_attn2(
    const unsigned short* __restrict__ h2, const float* __restrict__ gates,
    const int* __restrict__ gptr,
    float* __restrict__ hbuf, float* __restrict__ cbuf,
    float* __restrict__ qstar)
{
    int b = blockIdx.x, t = threadIdx.x;
    int wave = t >> 6, lane = t & 63;
    __shared__ float hs[FD];
    __shared__ float wm[4], wd[4], red[4][FD];

    if (t < FD) {
        const float* gr = gates + (size_t)b * 512;
        float ig = gr[t], fg = gr[FD + t], gg = gr[2 * FD + t], og = gr[3 * FD + t];
        float c = sigf(fg) * cbuf[(size_t)b * FD + t] + sigf(ig) * tanhf(gg);
        float h = sigf(og) * tanhf(c);
        cbuf[(size_t)b * FD + t] = c;
        hbuf[(size_t)b * FD + t] = h;
        hs[t] = h;
    }
    __syncthreads();

    int start = gptr[b], end = gptr[b + 1];
    float2 q = ((const float2*)hs)[lane];
    const unsigned int* H2 = (const unsigned int*)h2;  // row = 64 uints
    float mw = -INFINITY, dw = 0.f, rx = 0.f, ry = 0.f;
    for (int n = start + wave; n < end; n += 4) {
        unsigned int u = H2[(size_t)n * 64 + lane];
        float vx = b2f(u & 0xFFFFu), vy = b2f(u >> 16);
        float e = vx * q.x + vy * q.y;
#pragma unroll
        for (int off = 32; off; off >>= 1) e += __shfl_xor(e, off);
        float mn = fmaxf(mw, e);
        float corr = __expf(mw - mn);     // first iter: exp(-inf)=0
        float a = __expf(e - mn);
        rx = rx * corr + a * vx;
        ry = ry * corr + a * vy;
        dw = dw * corr + a;
        mw = mn;
    }
    if (lane == 0) wm[wave] = mw;
    __syncthreads();
    float M = fmaxf(fmaxf(wm[0], wm[1]), fmaxf(wm[2], wm[3]));
    float cr = (M == -INFINITY) ? 0.f : __expf(mw - M);
    red[wave][2 * lane] = rx * cr;
    red[wave][2 * lane + 1] = ry * cr;
    if (lane == 0) wd[wave] = dw * cr;
    __syncthreads();
    if (t < FD) {
        float r = red[0][t] + red[1][t] + red[2][t] + red[3][t];
        float den = wd[0] + wd[1] + wd[2] + wd[3];
        float rn = (den > 0.f) ? r / den : 0.f;
        qstar[(size_t)b * 256 + t] = hs[t];
        qstar[(size_t)b * 256 + FD + t] = rn;
    }
}

// ---- final projection: out = qstar @ Wp^T + bp ; 2 graphs per block ----
__global__ __launch_bounds__(256) void k_proj(
    const float* __restrict__ qstar, const float* __restrict__ Wp,
    const float* __restrict__ bp, float* __restrict__ out)
{
    __shared__ float qs[2][256];
    int t = threadIdx.x;
    int b0 = blockIdx.x * 2;
    qs[0][t] = qstar[(size_t)b0 * 256 + t];
    qs[1][t] = qstar[(size_t)(b0 + 1) * 256 + t];
    __syncthreads();
    int g = t >> 7, d = t & 127;
    const float4* w4 = (const float4*)(Wp + (size_t)d * 256);
    const float4* q4 = (const float4*)qs[g];
    float acc = bp[d];
    for (int k = 0; k < 64; k++) {
        float4 wv = w4[k], qv = q4[k];
        acc += qv.x*wv.x + qv.y*wv.y + qv.z*wv.z + qv.w*wv.w;
    }
    out[(size_t)(b0 + g) * FD + d] = acc;
}

__global__ void k_zero_out(float* __restrict__ out, int n) {
    int i = blockIdx.x * blockDim.x + threadIdx.x;
    if (i < n) out[i] = 0.f;
}

extern "C" void kernel_launch(void* const* d_in, const int* in_sizes, int n_in,
                              void* d_out, int out_size, void* d_ws, size_t ws_size,
                              hipStream_t stream) {
    const float* x   = (const float*)d_in[0];
    const int*  ei    = (const int*)d_in[1];
    const int*  batch = (const int*)d_in[2];
    const float* W1l = (const float*)d_in[3];
    const float* b1l = (const float*)d_in[4];
    const float* W1r = (const float*)d_in[5];
    const float* g1  = (const float*)d_in[6];
    const float* be1 = (const float*)d_in[7];
    const float* rm1 = (const float*)d_in[8];
    const float* rv1 = (const float*)d_in[9];
    const float* W2l = (const float*)d_in[10];
    const float* b2l = (const float*)d_in[11];
    const float* W2r = (const float*)d_in[12];
    const float* g2  = (const float*)d_in[13];
    const float* be2 = (const float*)d_in[14];
    const float* rm2 = (const float*)d_in[15];
    const float* rv2 = (const float*)d_in[16];
    const float* Wih = (const float*)d_in[17];
    const float* Whh = (const float*)d_in[18];
    const float* bih = (const float*)d_in[19];
    const float* bhh = (const float*)d_in[20];
    const float* Wp  = (const float*)d_in[21];
    const float* bp  = (const float*)d_in[22];
    float* out = (float*)d_out;

    auto al = [](size_t s) { return (s + 255) & ~(size_t)255; };
    size_t off_dcnt = 0;
    size_t off_cur  = off_dcnt + al((size_t)NN * 4);
    size_t off_gcnt = off_cur  + al((size_t)NN * 4);
    size_t off_gptr = off_gcnt + al((size_t)NG * 4);
    size_t off_rp   = off_gptr + al((size_t)(NG + 1) * 4);
    size_t off_srcs = off_rp   + al((size_t)(NN + 1) * 4);
    size_t off_xb   = off_srcs + al((size_t)NE * 4);            // also h2b
    size_t off_h1b  = off_xb   + al((size_t)NN * FD * 2);
    size_t off_Wb   = off_h1b  + al((size_t)NN * FD * 2);
    size_t off_C    = off_Wb   + al((size_t)256 * 128 * 2);
    size_t off_qs   = off_C    + al((size_t)NN * 256 * 2);
    size_t off_hb   = off_qs   + al((size_t)NG * 256 * 4);
    size_t off_cb   = off_hb   + al((size_t)NG * FD * 4);
    size_t off_gt   = off_cb   + al((size_t)NG * FD * 4);
    size_t need     = off_gt   + al((size_t)NG * 512 * 4);

    if (ws_size < need) {
        k_zero_out<<<(out_size + 255) / 256, 256, 0, stream>>>(out, out_size);
        return;
    }

    char* p = (char*)d_ws;
    int* dcnt    = (int*)(p + off_dcnt);
    int* cursor  = (int*)(p + off_cur);
    int* gcnt    = (int*)(p + off_gcnt);
    int* gptr    = (int*)(p + off_gptr);
    int* rowptr  = (int*)(p + off_rp);
    int* srcs    = (int*)(p + off_srcs);
    unsigned short* xb  = (unsigned short*)(p + off_xb);   // layer-1 input; later h2b
    unsigned short* h1b = (unsigned short*)(p + off_h1b);
    unsigned short* Wb  = (unsigned short*)(p + off_Wb);
    unsigned short* C   = (unsigned short*)(p + off_C);
    float* qstar = (float*)(p + off_qs);
    float* hbuf  = (float*)(p + off_hb);
    float* cbuf  = (float*)(p + off_cb);
    float* gates = (float*)(p + off_gt);
    unsigned short* h2b = xb;   // xb dead after layer-1 GEMM

    // one memset covers dcnt + cursor + gcnt (contiguous)
    hipMemsetAsync(p, 0, off_gptr, stream);

    // CSR build
    k_hist<<<(NE + 255) / 256, 256, 0, stream>>>(ei, batch, dcnt, gcnt);
    k_scan_nodes<<<1, 1024, 0, stream>>>(dcnt, rowptr);
    k_scan<<<1, NG, 0, stream>>>(gcnt, gptr);
    k_permute<<<(NE + 255) / 256, 256, 0, stream>>>(ei, rowptr, cursor, srcs);

    // layer 1: x -> xb (bf16), GEMM, gather -> h1b
    k_cvt_x<<<NN * FD / 1024, 256, 0, stream>>>(x, xb);
    k_cvt_w<<<128, 256, 0, stream>>>(W1l, W1r, Wb);
    k_mm<<<NN / 64, 256, 0, stream>>>(xb, Wb, C);
    k_gather2<<<NN / 8, 256, 0, stream>>>(C, srcs, rowptr, b1l, g1, be1, rm1, rv1, h1b);

    // layer 2: h1b -> GEMM -> gather -> h2b (aliases xb)
    k_cvt_w<<<128, 256, 0, stream>>>(W2l, W2r, Wb);
    k_mm<<<NN / 64, 256, 0, stream>>>(h1b, Wb, C);
    k_gather2<<<NN / 8, 256, 0, stream>>>(C, srcs, rowptr, b2l, g2, be2, rm2, rv2, h2b);

    // set2set state init
    k_init0<<<512, 256, 0, stream>>>(qstar, hbuf, cbuf);

    for (int step = 0; step < 3; step++) {
        k_gates<<<64, 256, 0, stream>>>(qstar, hbuf, Wih, Whh, bih, bhh, gates);
        k_attn2<<<NG, 256, 0, stream>>>(h2b, gates, gptr, hbuf, cbuf, qstar);
    }
    k_proj<<<NG / 2, 256, 0, stream>>>(qstar, Wp, bp, out);
}

// Round 8
// 435.724 us; speedup vs baseline: 4.4583x; 1.1515x over previous
//
#include <hip/hip_runtime.h>
#include <hip/hip_bf16.h>
#include <math.h>

#define NN 40000
#define NE 640000
#define NG 256
#define FD 128

typedef __attribute__((ext_vector_type(8))) short bf16x8;
typedef __attribute__((ext_vector_type(4))) float f32x4;

__device__ __forceinline__ float sigf(float x) { return 1.f / (1.f + __expf(-x)); }
__device__ __forceinline__ unsigned short f2b(float f) {
    unsigned int u = __float_as_uint(f);
    return (unsigned short)((u + 0x7FFFu + ((u >> 16) & 1u)) >> 16);
}
__device__ __forceinline__ float b2f(unsigned int u16) {
    return __uint_as_float(u16 << 16);
}

// ---- degree histogram per dst node (4 edges/thread, dcnt only) ----
__global__ void k_hist4(const int* __restrict__ ei, int* __restrict__ dcnt) {
    int i = blockIdx.x * 256 + threadIdx.x;      // grid 625 -> 160000, x4 edges
    int4 d = ((const int4*)(ei + NE))[i];
    atomicAdd(&dcnt[d.x], 1);
    atomicAdd(&dcnt[d.y], 1);
    atomicAdd(&dcnt[d.z], 1);
    atomicAdd(&dcnt[d.w], 1);
}

// ---- gptr from SORTED batch via boundary detection (no atomics) ----
__global__ void k_gptr(const int* __restrict__ batch, int* __restrict__ gptr) {
    int i = blockIdx.x * 256 + threadIdx.x;
    if (i >= NN) return;
    int b = batch[i];
    int pb = (i == 0) ? -1 : batch[i - 1];
    for (int g = pb + 1; g <= b; g++) gptr[g] = i;
    if (i == NN - 1) {
        for (int g = b + 1; g <= NG; g++) gptr[g] = NN;
    }
}

// ---- exclusive scan of 40000 node degrees -> rowptr[NN+1]; 1 block, 1024 thr ----
#define SCH 40  // 1024 * 40 = 40960 >= NN
__global__ __launch_bounds__(1024) void k_scan_nodes(const int* __restrict__ dcnt,
                                                     int* __restrict__ rowptr) {
    __shared__ int s[1024];
    int t = threadIdx.x;
    int base = t * SCH;
    int local = 0;
#pragma unroll
    for (int i = 0; i < SCH; i++) {
        int idx = base + i;
        if (idx < NN) local += dcnt[idx];
    }
    s[t] = local;
    __syncthreads();
    for (int off = 1; off < 1024; off <<= 1) {
        int v = (t >= off) ? s[t - off] : 0;
        __syncthreads();
        s[t] += v;
        __syncthreads();
    }
    int run = s[t] - local;  // exclusive prefix
#pragma unroll
    for (int i = 0; i < SCH; i++) {
        int idx = base + i;
        if (idx < NN) { rowptr[idx] = run; run += dcnt[idx]; }
    }
    if (t == 0) rowptr[NN] = s[1023];
}

// ---- bucket edge sources by dst: srcs[rowptr[dst]...] = src ----
__global__ void k_permute(const int* __restrict__ ei, const int* __restrict__ rowptr,
                          int* __restrict__ cursor, int* __restrict__ srcs) {
    int i = blockIdx.x * blockDim.x + threadIdx.x;
    if (i >= NE) return;
    int dst = ei[NE + i];
    int pos = atomicAdd(&cursor[dst], 1);
    srcs[rowptr[dst] + pos] = ei[i];
}

// ---- fp32 -> bf16 conversions ----
__global__ void k_cvt_x(const float* __restrict__ in, unsigned short* __restrict__ out) {
    int i = (blockIdx.x * 256 + threadIdx.x) * 4;  // grid 5000 -> 5,120,000
    float4 v = *(const float4*)(in + i);
    ushort4 o;
    o.x = f2b(v.x); o.y = f2b(v.y); o.z = f2b(v.z); o.w = f2b(v.w);
    *(ushort4*)(out + i) = o;
}
// Wb[0:32768) = layer1 [Wl rows | Wr rows], Wb[32768:65536) = layer2
__global__ void k_cvt_w2(const float* __restrict__ W1l, const float* __restrict__ W1r,
                         const float* __restrict__ W2l, const float* __restrict__ W2r,
                         unsigned short* __restrict__ Wb) {
    int i = blockIdx.x * 256 + threadIdx.x;   // grid 256 -> 65536
    float v;
    if (i < 16384)      v = W1l[i];
    else if (i < 32768) v = W1r[i - 16384];
    else if (i < 49152) v = W2l[i - 32768];
    else                v = W2r[i - 49152];
    Wb[i] = f2b(v);
}

// ---- MFMA GEMM: C[n][0:256] = A[n][0:128] @ Wb^T  (A,W,C all bf16) ----
// Block: 256 thr (4 waves), 64 A-rows; W fully staged in LDS (64 KB, XOR-swizzled).
// mfma_f32_16x16x32_bf16: A: m=lane&15, k=quad*8+j; B: n=lane&15 (row of W);
// D: col(n)=lane&15, row(m)=quad*4+reg.
__global__ __launch_bounds__(256) void k_mm(
    const unsigned short* __restrict__ A,   // [NN][128] bf16
    const unsigned short* __restrict__ W,   // [256][128] bf16
    unsigned short* __restrict__ C)         // [NN][256] bf16
{
    __shared__ unsigned short Ws[256 * 128];   // 64 KB
    int t = threadIdx.x;
    {
        const uint4* Wg = (const uint4*)W;     // 4096 x 16B, 16 per row
#pragma unroll
        for (int i = 0; i < 16; i++) {
            int f = i * 256 + t;
            int row = f >> 4, c = f & 15;
            int cs = c ^ (row & 15);           // XOR swizzle on 16B chunks
            *(uint4*)&Ws[row * 128 + cs * 8] = Wg[f];
        }
    }
    __syncthreads();
    int w = t >> 6, lane = t & 63;
    int ln = lane & 15, quad = lane >> 4;
    int m0 = blockIdx.x * 64 + w * 16;
    bf16x8 a[4];
    const unsigned short* Arow = A + (size_t)(m0 + ln) * 128;
#pragma unroll
    for (int ks = 0; ks < 4; ks++)
        a[ks] = *(const bf16x8*)(Arow + ks * 32 + quad * 8);
    for (int nt = 0; nt < 16; nt++) {
        int n0 = nt * 16;
        int row = n0 + ln;
        f32x4 acc = {0.f, 0.f, 0.f, 0.f};
#pragma unroll
        for (int ks = 0; ks < 4; ks++) {
            int c = ks * 4 + quad;
            bf16x8 b = *(const bf16x8*)&Ws[row * 128 + (c ^ (row & 15)) * 8];
            acc = __builtin_amdgcn_mfma_f32_16x16x32_bf16(a[ks], b, acc, 0, 0, 0);
        }
        size_t base = (size_t)(m0 + quad * 4) * 256 + n0 + ln;
#pragma unroll
        for (int r = 0; r < 4; r++)
            C[base + (size_t)r * 256] = f2b(acc[r]);
    }
}

// ---- gather + BN + ReLU: H[n] = relu(scale*(mean_j C[j][0:128] + bl + C[n][128:256] - rm) + bt) ----
__global__ __launch_bounds__(256) void k_gather2(
    const unsigned short* __restrict__ C, const int* __restrict__ srcs,
    const int* __restrict__ rowptr,
    const float* __restrict__ bl,
    const float* __restrict__ gam, const float* __restrict__ bet,
    const float* __restrict__ rme, const float* __restrict__ rva,
    unsigned short* __restrict__ H)
{
    int t = threadIdx.x;
    int hw = t >> 5, l5 = t & 31;
    int node = blockIdx.x * 8 + hw;
    int s0 = rowptr[node], e0 = rowptr[node + 1];
    const uint2* C2 = (const uint2*)C;   // row = 64 uint2 (256 bf16)
    float a0 = 0.f, a1 = 0.f, a2 = 0.f, a3 = 0.f;
    int i = s0;
    for (; i + 7 < e0; i += 8) {
        uint2 v0 = C2[(size_t)srcs[i]     * 64 + l5];
        uint2 v1 = C2[(size_t)srcs[i + 1] * 64 + l5];
        uint2 v2 = C2[(size_t)srcs[i + 2] * 64 + l5];
        uint2 v3 = C2[(size_t)srcs[i + 3] * 64 + l5];
        uint2 v4 = C2[(size_t)srcs[i + 4] * 64 + l5];
        uint2 v5 = C2[(size_t)srcs[i + 5] * 64 + l5];
        uint2 v6 = C2[(size_t)srcs[i + 6] * 64 + l5];
        uint2 v7 = C2[(size_t)srcs[i + 7] * 64 + l5];
        a0 += b2f(v0.x & 0xFFFFu) + b2f(v1.x & 0xFFFFu) + b2f(v2.x & 0xFFFFu) + b2f(v3.x & 0xFFFFu)
            + b2f(v4.x & 0xFFFFu) + b2f(v5.x & 0xFFFFu) + b2f(v6.x & 0xFFFFu) + b2f(v7.x & 0xFFFFu);
        a1 += b2f(v0.x >> 16) + b2f(v1.x >> 16) + b2f(v2.x >> 16) + b2f(v3.x >> 16)
            + b2f(v4.x >> 16) + b2f(v5.x >> 16) + b2f(v6.x >> 16) + b2f(v7.x >> 16);
        a2 += b2f(v0.y & 0xFFFFu) + b2f(v1.y & 0xFFFFu) + b2f(v2.y & 0xFFFFu) + b2f(v3.y & 0xFFFFu)
            + b2f(v4.y & 0xFFFFu) + b2f(v5.y & 0xFFFFu) + b2f(v6.y & 0xFFFFu) + b2f(v7.y & 0xFFFFu);
        a3 += b2f(v0.y >> 16) + b2f(v1.y >> 16) + b2f(v2.y >> 16) + b2f(v3.y >> 16)
            + b2f(v4.y >> 16) + b2f(v5.y >> 16) + b2f(v6.y >> 16) + b2f(v7.y >> 16);
    }
    for (; i < e0; i++) {
        uint2 v = C2[(size_t)srcs[i] * 64 + l5];
        a0 += b2f(v.x & 0xFFFFu); a1 += b2f(v.x >> 16);
        a2 += b2f(v.y & 0xFFFFu); a3 += b2f(v.y >> 16);
    }
    float inv = 1.0f / fmaxf((float)(e0 - s0), 1.0f);
    uint2 yr = C2[(size_t)node * 64 + 32 + l5];
    float y0 = a0 * inv + b2f(yr.x & 0xFFFFu);
    float y1 = a1 * inv + b2f(yr.x >> 16);
    float y2 = a2 * inv + b2f(yr.y & 0xFFFFu);
    float y3 = a3 * inv + b2f(yr.y >> 16);
    float4 g4  = ((const float4*)gam)[l5];
    float4 rv4 = ((const float4*)rva)[l5];
    float4 rm4 = ((const float4*)rme)[l5];
    float4 bt4 = ((const float4*)bet)[l5];
    float4 bb4 = ((const float4*)bl)[l5];
    float z0 = fmaxf(g4.x * rsqrtf(rv4.x + 1e-5f) * (y0 + bb4.x - rm4.x) + bt4.x, 0.f);
    float z1 = fmaxf(g4.y * rsqrtf(rv4.y + 1e-5f) * (y1 + bb4.y - rm4.y) + bt4.y, 0.f);
    float z2 = fmaxf(g4.z * rsqrtf(rv4.z + 1e-5f) * (y2 + bb4.z - rm4.z) + bt4.z, 0.f);
    float z3 = fmaxf(g4.w * rsqrtf(rv4.w + 1e-5f) * (y3 + bb4.w - rm4.w) + bt4.w, 0.f);
    ushort4 o;
    o.x = f2b(z0); o.y = f2b(z1); o.z = f2b(z2); o.w = f2b(z3);
    *(ushort4*)(H + (size_t)node * 128 + l5 * 4) = o;
}

// ---- step-0 LSTM: qstar=0,h=0 => gates = bih+bhh (graph-independent, exact) ----
__global__ __launch_bounds__(256) void k_lstm0(
    const float* __restrict__ bih, const float* __restrict__ bhh,
    float* __restrict__ hbuf, float* __restrict__ cbuf)
{
    int i = blockIdx.x * 256 + threadIdx.x;  // grid 128 -> 32768 (256 graphs x 128)
    int d = i & 127;
    float ig = bih[d] + bhh[d];
    float gg = bih[256 + d] + bhh[256 + d];
    float og = bih[384 + d] + bhh[384 + d];
    float c = sigf(ig) * tanhf(gg);          // f-gate * c_prev(=0) dropped
    float h = sigf(og) * tanhf(c);
    hbuf[i] = h; cbuf[i] = c;
}

// ---- gates = qstar @ Wih^T + h @ Whh^T + bih + bhh ; tile [32 graphs x 64 rows] ----
__global__ __launch_bounds__(256) void k_gates(
    const float* __restrict__ qstar, const float* __restrict__ hbuf,
    const float* __restrict__ Wih, const float* __restrict__ Whh,
    const float* __restrict__ bih, const float* __restrict__ bhh,
    float* __restrict__ gates)
{
    __shared__ float X[32][384];
    int t = threadIdx.x;
    int gt = blockIdx.x & 7, rt = blockIdx.x >> 3;
    int G0 = gt * 32, R0 = rt * 64;
    const float4* q4 = (const float4*)qstar;  // [256][64] float4
    const float4* h4 = (const float4*)hbuf;   // [256][32] float4
#pragma unroll
    for (int i = 0; i < 12; i++) {
        int f = i * 256 + t;          // 0..3071
        int g = f / 96, c4 = f % 96;
        float4 v = (c4 < 64) ? q4[(size_t)(G0 + g) * 64 + c4]
                             : h4[(size_t)(G0 + g) * 32 + (c4 - 64)];
        ((float4*)X[g])[c4] = v;
    }
    __syncthreads();
    int r = t & 63, gq = t >> 6;
    int R = R0 + r;
    const float4* wi4 = (const float4*)(Wih + (size_t)R * 256);
    const float4* wh4 = (const float4*)(Whh + (size_t)R * 128);
    float bias = bih[R] + bhh[R];
    float acc[8];
#pragma unroll
    for (int j = 0; j < 8; j++) acc[j] = bias;
    for (int k = 0; k < 64; k++) {
        float4 wv = wi4[k];
#pragma unroll
        for (int j = 0; j < 8; j++) {
            float4 xv = ((const float4*)X[gq + 4 * j])[k];
            acc[j] += xv.x*wv.x + xv.y*wv.y + xv.z*wv.z + xv.w*wv.w;
        }
    }
    for (int k = 0; k < 32; k++) {
        float4 wv = wh4[k];
#pragma unroll
        for (int j = 0; j < 8; j++) {
            float4 xv = ((const float4*)X[gq + 4 * j])[64 + k];
            acc[j] += xv.x*wv.x + xv.y*wv.y + xv.z*wv.z + xv.w*wv.w;
        }
    }
#pragma unroll
    for (int j = 0; j < 8; j++)
        gates[(size_t)(G0 + gq + 4 * j) * 512 + R] = acc[j];
}

// ---- fused (optional LSTM pointwise) + online-softmax attention + qstar update ----
__global__ __launch_bounds__(256) void k_attn2(
    const unsigned short* __restrict__ h2, const float* __restrict__ gates,
    const int* __restrict__ gptr,
    float* __restrict__ hbuf, float* __restrict__ cbuf,
    float* __restrict__ qstar, int do_lstm)
{
    int b = blockIdx.x, t = threadIdx.x;
    int wave = t >> 6, lane = t & 63;
    __shared__ float hs[FD];
    __shared__ float wm[4], wd[4], red[4][FD];

    if (t < FD) {
        if (do_lstm) {
            const float* gr = gates + (size_t)b * 512;
            float ig = gr[t], fg = gr[FD + t], gg = gr[2 * FD + t], og = gr[3 * FD + t];
            float c = sigf(fg) * cbuf[(size_t)b * FD + t] + sigf(ig) * tanhf(gg);
            float h = sigf(og) * tanhf(c);
            cbuf[(size_t)b * FD + t] = c;
            hbuf[(size_t)b * FD + t] = h;
            hs[t] = h;
        } else {
            hs[t] = hbuf[(size_t)b * FD + t];
        }
    }
    __syncthreads();

    int start = gptr[b], end = gptr[b + 1];
    float2 q = ((const float2*)hs)[lane];
    const unsigned int* H2 = (const unsigned int*)h2;  // row = 64 uints
    float mw = -INFINITY, dw = 0.f, rx = 0.f, ry = 0.f;
    for (int n = start + wave; n < end; n += 4) {
        unsigned int u = H2[(size_t)n * 64 + lane];
        float vx = b2f(u & 0xFFFFu), vy = b2f(u >> 16);
        float e = vx * q.x + vy * q.y;
#pragma unroll
        for (int off = 32; off; off >>= 1) e += __shfl_xor(e, off);
        float mn = fmaxf(mw, e);
        float corr = __expf(mw - mn);     // first iter: exp(-inf)=0
        float a = __expf(e - mn);
        rx = rx * corr + a * vx;
        ry = ry * corr + a * vy;
        dw = dw * corr + a;
        mw = mn;
    }
    if (lane == 0) wm[wave] = mw;
    __syncthreads();
    float M = fmaxf(fmaxf(wm[0], wm[1]), fmaxf(wm[2], wm[3]));
    float cr = (M == -INFINITY) ? 0.f : __expf(mw - M);
    red[wave][2 * lane] = rx * cr;
    red[wave][2 * lane + 1] = ry * cr;
    if (lane == 0) wd[wave] = dw * cr;
    __syncthreads();
    if (t < FD) {
        float r = red[0][t] + red[1][t] + red[2][t] + red[3][t];
        float den = wd[0] + wd[1] + wd[2] + wd[3];
        float rn = (den > 0.f) ? r / den : 0.f;
        qstar[(size_t)b * 256 + t] = hs[t];
        qstar[(size_t)b * 256 + FD + t] = rn;
    }
}

// ---- final projection: out = qstar @ Wp^T + bp ; 2 graphs per block ----
__global__ __launch_bounds__(256) void k_proj(
    const float* __restrict__ qstar, const float* __restrict__ Wp,
    const float* __restrict__ bp, float* __restrict__ out)
{
    __shared__ float qs[2][256];
    int t = threadIdx.x;
    int b0 = blockIdx.x * 2;
    qs[0][t] = qstar[(size_t)b0 * 256 + t];
    qs[1][t] = qstar[(size_t)(b0 + 1) * 256 + t];
    __syncthreads();
    int g = t >> 7, d = t & 127;
    const float4* w4 = (const float4*)(Wp + (size_t)d * 256);
    const float4* q4 = (const float4*)qs[g];
    float acc = bp[d];
    for (int k = 0; k < 64; k++) {
        float4 wv = w4[k], qv = q4[k];
        acc += qv.x*wv.x + qv.y*wv.y + qv.z*wv.z + qv.w*wv.w;
    }
    out[(size_t)(b0 + g) * FD + d] = acc;
}

__global__ void k_zero_out(float* __restrict__ out, int n) {
    int i = blockIdx.x * blockDim.x + threadIdx.x;
    if (i < n) out[i] = 0.f;
}

extern "C" void kernel_launch(void* const* d_in, const int* in_sizes, int n_in,
                              void* d_out, int out_size, void* d_ws, size_t ws_size,
                              hipStream_t stream) {
    const float* x   = (const float*)d_in[0];
    const int*  ei    = (const int*)d_in[1];
    const int*  batch = (const int*)d_in[2];
    const float* W1l = (const float*)d_in[3];
    const float* b1l = (const float*)d_in[4];
    const float* W1r = (const float*)d_in[5];
    const float* g1  = (const float*)d_in[6];
    const float* be1 = (const float*)d_in[7];
    const float* rm1 = (const float*)d_in[8];
    const float* rv1 = (const float*)d_in[9];
    const float* W2l = (const float*)d_in[10];
    const float* b2l = (const float*)d_in[11];
    const float* W2r = (const float*)d_in[12];
    const float* g2  = (const float*)d_in[13];
    const float* be2 = (const float*)d_in[14];
    const float* rm2 = (const float*)d_in[15];
    const float* rv2 = (const float*)d_in[16];
    const float* Wih = (const float*)d_in[17];
    const float* Whh = (const float*)d_in[18];
    const float* bih = (const float*)d_in[19];
    const float* bhh = (const float*)d_in[20];
    const float* Wp  = (const float*)d_in[21];
    const float* bp  = (const float*)d_in[22];
    float* out = (float*)d_out;

    auto al = [](size_t s) { return (s + 255) & ~(size_t)255; };
    size_t off_dcnt = 0;
    size_t off_cur  = off_dcnt + al((size_t)NN * 4);
    size_t off_gptr = off_cur  + al((size_t)NN * 4);
    size_t off_rp   = off_gptr + al((size_t)(NG + 1) * 4);
    size_t off_srcs = off_rp   + al((size_t)(NN + 1) * 4);
    size_t off_xb   = off_srcs + al((size_t)NE * 4);            // also h2b
    size_t off_h1b  = off_xb   + al((size_t)NN * FD * 2);
    size_t off_Wb   = off_h1b  + al((size_t)NN * FD * 2);
    size_t off_C    = off_Wb   + al((size_t)2 * 256 * 128 * 2);
    size_t off_qs   = off_C    + al((size_t)NN * 256 * 2);
    size_t off_hb   = off_qs   + al((size_t)NG * 256 * 4);
    size_t off_cb   = off_hb   + al((size_t)NG * FD * 4);
    size_t off_gt   = off_cb   + al((size_t)NG * FD * 4);
    size_t need     = off_gt   + al((size_t)NG * 512 * 4);

    if (ws_size < need) {
        k_zero_out<<<(out_size + 255) / 256, 256, 0, stream>>>(out, out_size);
        return;
    }

    char* p = (char*)d_ws;
    int* dcnt    = (int*)(p + off_dcnt);
    int* cursor  = (int*)(p + off_cur);
    int* gptr    = (int*)(p + off_gptr);
    int* rowptr  = (int*)(p + off_rp);
    int* srcs    = (int*)(p + off_srcs);
    unsigned short* xb  = (unsigned short*)(p + off_xb);   // layer-1 input; later h2b
    unsigned short* h1b = (unsigned short*)(p + off_h1b);
    unsigned short* Wb  = (unsigned short*)(p + off_Wb);
    unsigned short* C   = (unsigned short*)(p + off_C);
    float* qstar = (float*)(p + off_qs);
    float* hbuf  = (float*)(p + off_hb);
    float* cbuf  = (float*)(p + off_cb);
    float* gates = (float*)(p + off_gt);
    unsigned short* h2b = xb;   // xb dead after layer-1 GEMM

    // memset covers dcnt + cursor (contiguous)
    hipMemsetAsync(p, 0, off_gptr, stream);

    // CSR build (gptr atomic-free from sorted batch)
    k_hist4<<<NE / 1024, 256, 0, stream>>>(ei, dcnt);
    k_gptr<<<(NN + 255) / 256, 256, 0, stream>>>(batch, gptr);
    k_scan_nodes<<<1, 1024, 0, stream>>>(dcnt, rowptr);
    k_permute<<<(NE + 255) / 256, 256, 0, stream>>>(ei, rowptr, cursor, srcs);

    // weight + input conversion
    k_cvt_x<<<NN * FD / 1024, 256, 0, stream>>>(x, xb);
    k_cvt_w2<<<256, 256, 0, stream>>>(W1l, W1r, W2l, W2r, Wb);

    // layer 1: xb -> GEMM -> gather -> h1b
    k_mm<<<NN / 64, 256, 0, stream>>>(xb, Wb, C);
    k_gather2<<<NN / 8, 256, 0, stream>>>(C, srcs, rowptr, b1l, g1, be1, rm1, rv1, h1b);

    // layer 2: h1b -> GEMM -> gather -> h2b (aliases xb)
    k_mm<<<NN / 64, 256, 0, stream>>>(h1b, Wb + 32768, C);
    k_gather2<<<NN / 8, 256, 0, stream>>>(C, srcs, rowptr, b2l, g2, be2, rm2, rv2, h2b);

    // set2set: step 0 LSTM is bias-only (exact; qstar=0,h=0)
    k_lstm0<<<128, 256, 0, stream>>>(bih, bhh, hbuf, cbuf);
    k_attn2<<<NG, 256, 0, stream>>>(h2b, gates, gptr, hbuf, cbuf, qstar, 0);
    for (int step = 1; step < 3; step++) {
        k_gates<<<64, 256, 0, stream>>>(qstar, hbuf, Wih, Whh, bih, bhh, gates);
        k_attn2<<<NG, 256, 0, stream>>>(h2b, gates, gptr, hbuf, cbuf, qstar, 1);
    }
    k_proj<<<NG / 2, 256, 0, stream>>>(qstar, Wp, bp, out);
}

// Round 9
// 365.170 us; speedup vs baseline: 5.3196x; 1.1932x over previous
//
#include <hip/hip_runtime.h>
#include <hip/hip_bf16.h>
#include <math.h>

#define NN 40000
#define NE 640000
#define NG 256
#define FD 128

typedef __attribute__((ext_vector_type(8))) short bf16x8;
typedef __attribute__((ext_vector_type(4))) float f32x4;

__device__ __forceinline__ float sigf(float x) { return 1.f / (1.f + __expf(-x)); }
__device__ __forceinline__ unsigned short f2b(float f) {
    unsigned int u = __float_as_uint(f);
    return (unsigned short)((u + 0x7FFFu + ((u >> 16) & 1u)) >> 16);
}
__device__ __forceinline__ float b2f(unsigned int u16) {
    return __uint_as_float(u16 << 16);
}

// ---- degree histogram per dst node (4 edges/thread, dcnt only) ----
__global__ void k_hist4(const int* __restrict__ ei, int* __restrict__ dcnt) {
    int i = blockIdx.x * 256 + threadIdx.x;      // grid 625 -> 160000, x4 edges
    int4 d = ((const int4*)(ei + NE))[i];
    atomicAdd(&dcnt[d.x], 1);
    atomicAdd(&dcnt[d.y], 1);
    atomicAdd(&dcnt[d.z], 1);
    atomicAdd(&dcnt[d.w], 1);
}

// ---- gptr from SORTED batch via boundary detection (no atomics) ----
__global__ void k_gptr(const int* __restrict__ batch, int* __restrict__ gptr) {
    int i = blockIdx.x * 256 + threadIdx.x;
    if (i >= NN) return;
    int b = batch[i];
    int pb = (i == 0) ? -1 : batch[i - 1];
    for (int g = pb + 1; g <= b; g++) gptr[g] = i;
    if (i == NN - 1) {
        for (int g = b + 1; g <= NG; g++) gptr[g] = NN;
    }
}

// ---- 3-phase parallel exclusive scan of dcnt -> rowptr ----
// Phase A: per-block (1024 elems) totals.
__global__ __launch_bounds__(1024) void k_scan_part(const int* __restrict__ dcnt,
                                                    int* __restrict__ bsum) {
    int t = threadIdx.x;
    int idx = blockIdx.x * 1024 + t;
    int v = (idx < NN) ? dcnt[idx] : 0;
    int s = v;
#pragma unroll
    for (int off = 32; off; off >>= 1) s += __shfl_xor(s, off);
    __shared__ int ws[16];
    if ((t & 63) == 0) ws[t >> 6] = s;
    __syncthreads();
    if (t == 0) {
        int tot = 0;
#pragma unroll
        for (int i = 0; i < 16; i++) tot += ws[i];
        bsum[blockIdx.x] = tot;
    }
}
// Phase B: scan 40 block sums -> boff (exclusive); also rowptr[NN] = total.
__global__ void k_scan_boff(const int* __restrict__ bsum, int* __restrict__ boff,
                            int* __restrict__ rowptr) {
    __shared__ int s[64];
    int t = threadIdx.x;  // 64 threads
    int v = (t < 40) ? bsum[t] : 0;
    s[t] = v;
    __syncthreads();
    for (int off = 1; off < 64; off <<= 1) {
        int u = (t >= off) ? s[t - off] : 0;
        __syncthreads();
        s[t] += u;
        __syncthreads();
    }
    if (t < 40) boff[t] = s[t] - v;
    if (t == 39) rowptr[NN] = s[39];
}
// Phase C: block-local exclusive scan + block offset -> rowptr.
__global__ __launch_bounds__(1024) void k_scan_fin(const int* __restrict__ dcnt,
                                                   const int* __restrict__ boff,
                                                   int* __restrict__ rowptr) {
    __shared__ int s[1024];
    int t = threadIdx.x;
    int idx = blockIdx.x * 1024 + t;
    int v = (idx < NN) ? dcnt[idx] : 0;
    s[t] = v;
    __syncthreads();
    for (int off = 1; off < 1024; off <<= 1) {
        int u = (t >= off) ? s[t - off] : 0;
        __syncthreads();
        s[t] += u;
        __syncthreads();
    }
    if (idx < NN) rowptr[idx] = s[t] - v + boff[blockIdx.x];
}

// ---- bucket edge sources by dst: srcs[rowptr[dst]...] = src ----
__global__ void k_permute(const int* __restrict__ ei, const int* __restrict__ rowptr,
                          int* __restrict__ cursor, int* __restrict__ srcs) {
    int i = blockIdx.x * blockDim.x + threadIdx.x;
    if (i >= NE) return;
    int dst = ei[NE + i];
    int pos = atomicAdd(&cursor[dst], 1);
    srcs[rowptr[dst] + pos] = ei[i];
}

// ---- fp32 -> bf16 weight conversion (both layers, one dispatch) ----
// Wb[0:32768) = layer1 [Wl | Wr], Wb[32768:65536) = layer2.
__global__ void k_cvt_w(const float* __restrict__ W1l, const float* __restrict__ W1r,
                        const float* __restrict__ W2l, const float* __restrict__ W2r,
                        unsigned short* __restrict__ Wb) {
    int j4 = blockIdx.x * 256 + threadIdx.x;   // grid 64 -> 16384 float4s
    int seg = j4 >> 12, off4 = j4 & 4095;
    const float* W = (seg == 0) ? W1l : (seg == 1) ? W1r : (seg == 2) ? W2l : W2r;
    float4 v = ((const float4*)W)[off4];
    ushort4 o;
    o.x = f2b(v.x); o.y = f2b(v.y); o.z = f2b(v.z); o.w = f2b(v.w);
    *(ushort4*)(Wb + (size_t)j4 * 4) = o;
}

// ---- MFMA GEMM: C[n][0:256] = A[n][0:128] @ Wb^T  (C bf16) ----
// a_fp32: A is fp32 (layer 1, converts in-regs); else A is bf16.
// Block: 256 thr (4 waves), 64 A-rows; W staged in LDS (64 KB, XOR-swizzled).
// mfma_f32_16x16x32_bf16: A: m=lane&15, k=quad*8+j; B: n=lane&15 (row of W);
// D: col(n)=lane&15, row(m)=quad*4+reg.
__global__ __launch_bounds__(256) void k_mm(
    const void* __restrict__ Av, int a_fp32,
    const unsigned short* __restrict__ W,   // [256][128] bf16
    unsigned short* __restrict__ C)         // [NN][256] bf16
{
    __shared__ unsigned short Ws[256 * 128];   // 64 KB
    int t = threadIdx.x;
    {
        const uint4* Wg = (const uint4*)W;     // 4096 x 16B, 16 per row
#pragma unroll
        for (int i = 0; i < 16; i++) {
            int f = i * 256 + t;
            int row = f >> 4, c = f & 15;
            int cs = c ^ (row & 15);           // XOR swizzle on 16B chunks
            *(uint4*)&Ws[row * 128 + cs * 8] = Wg[f];
        }
    }
    __syncthreads();
    int w = t >> 6, lane = t & 63;
    int ln = lane & 15, quad = lane >> 4;
    int m0 = blockIdx.x * 64 + w * 16;
    bf16x8 a[4];
    if (a_fp32) {
        const float* Arow = (const float*)Av + (size_t)(m0 + ln) * 128;
#pragma unroll
        for (int ks = 0; ks < 4; ks++) {
            float4 u0 = *(const float4*)(Arow + ks * 32 + quad * 8);
            float4 u1 = *(const float4*)(Arow + ks * 32 + quad * 8 + 4);
            unsigned short tmp[8];
            tmp[0] = f2b(u0.x); tmp[1] = f2b(u0.y); tmp[2] = f2b(u0.z); tmp[3] = f2b(u0.w);
            tmp[4] = f2b(u1.x); tmp[5] = f2b(u1.y); tmp[6] = f2b(u1.z); tmp[7] = f2b(u1.w);
            a[ks] = *(const bf16x8*)tmp;
        }
    } else {
        const unsigned short* Arow = (const unsigned short*)Av + (size_t)(m0 + ln) * 128;
#pragma unroll
        for (int ks = 0; ks < 4; ks++)
            a[ks] = *(const bf16x8*)(Arow + ks * 32 + quad * 8);
    }
    for (int nt = 0; nt < 16; nt++) {
        int n0 = nt * 16;
        int row = n0 + ln;
        f32x4 acc = {0.f, 0.f, 0.f, 0.f};
#pragma unroll
        for (int ks = 0; ks < 4; ks++) {
            int c = ks * 4 + quad;
            bf16x8 b = *(const bf16x8*)&Ws[row * 128 + (c ^ (row & 15)) * 8];
            acc = __builtin_amdgcn_mfma_f32_16x16x32_bf16(a[ks], b, acc, 0, 0, 0);
        }
        size_t base = (size_t)(m0 + quad * 4) * 256 + n0 + ln;
#pragma unroll
        for (int r = 0; r < 4; r++)
            C[base + (size_t)r * 256] = f2b(acc[r]);
    }
}

// ---- gather + BN + ReLU: H[n] = relu(scale*(mean_j C[j][0:128] + bl + C[n][128:256] - rm) + bt) ----
__global__ __launch_bounds__(256) void k_gather2(
    const unsigned short* __restrict__ C, const int* __restrict__ srcs,
    const int* __restrict__ rowptr,
    const float* __restrict__ bl,
    const float* __restrict__ gam, const float* __restrict__ bet,
    const float* __restrict__ rme, const float* __restrict__ rva,
    unsigned short* __restrict__ H)
{
    int t = threadIdx.x;
    int hw = t >> 5, l5 = t & 31;
    int node = blockIdx.x * 8 + hw;
    int s0 = rowptr[node], e0 = rowptr[node + 1];
    const uint2* C2 = (const uint2*)C;   // row = 64 uint2 (256 bf16)
    float a0 = 0.f, a1 = 0.f, a2 = 0.f, a3 = 0.f;
    int i = s0;
    for (; i + 7 < e0; i += 8) {
        uint2 v0 = C2[(size_t)srcs[i]     * 64 + l5];
        uint2 v1 = C2[(size_t)srcs[i + 1] * 64 + l5];
        uint2 v2 = C2[(size_t)srcs[i + 2] * 64 + l5];
        uint2 v3 = C2[(size_t)srcs[i + 3] * 64 + l5];
        uint2 v4 = C2[(size_t)srcs[i + 4] * 64 + l5];
        uint2 v5 = C2[(size_t)srcs[i + 5] * 64 + l5];
        uint2 v6 = C2[(size_t)srcs[i + 6] * 64 + l5];
        uint2 v7 = C2[(size_t)srcs[i + 7] * 64 + l5];
        a0 += b2f(v0.x & 0xFFFFu) + b2f(v1.x & 0xFFFFu) + b2f(v2.x & 0xFFFFu) + b2f(v3.x & 0xFFFFu)
            + b2f(v4.x & 0xFFFFu) + b2f(v5.x & 0xFFFFu) + b2f(v6.x & 0xFFFFu) + b2f(v7.x & 0xFFFFu);
        a1 += b2f(v0.x >> 16) + b2f(v1.x >> 16) + b2f(v2.x >> 16) + b2f(v3.x >> 16)
            + b2f(v4.x >> 16) + b2f(v5.x >> 16) + b2f(v6.x >> 16) + b2f(v7.x >> 16);
        a2 += b2f(v0.y & 0xFFFFu) + b2f(v1.y & 0xFFFFu) + b2f(v2.y & 0xFFFFu) + b2f(v3.y & 0xFFFFu)
            + b2f(v4.y & 0xFFFFu) + b2f(v5.y & 0xFFFFu) + b2f(v6.y & 0xFFFFu) + b2f(v7.y & 0xFFFFu);
        a3 += b2f(v0.y >> 16) + b2f(v1.y >> 16) + b2f(v2.y >> 16) + b2f(v3.y >> 16)
            + b2f(v4.y >> 16) + b2f(v5.y >> 16) + b2f(v6.y >> 16) + b2f(v7.y >> 16);
    }
    for (; i < e0; i++) {
        uint2 v = C2[(size_t)srcs[i] * 64 + l5];
        a0 += b2f(v.x & 0xFFFFu); a1 += b2f(v.x >> 16);
        a2 += b2f(v.y & 0xFFFFu); a3 += b2f(v.y >> 16);
    }
    float inv = 1.0f / fmaxf((float)(e0 - s0), 1.0f);
    uint2 yr = C2[(size_t)node * 64 + 32 + l5];
    float y0 = a0 * inv + b2f(yr.x & 0xFFFFu);
    float y1 = a1 * inv + b2f(yr.x >> 16);
    float y2 = a2 * inv + b2f(yr.y & 0xFFFFu);
    float y3 = a3 * inv + b2f(yr.y >> 16);
    float4 g4  = ((const float4*)gam)[l5];
    float4 rv4 = ((const float4*)rva)[l5];
    float4 rm4 = ((const float4*)rme)[l5];
    float4 bt4 = ((const float4*)bet)[l5];
    float4 bb4 = ((const float4*)bl)[l5];
    float z0 = fmaxf(g4.x * rsqrtf(rv4.x + 1e-5f) * (y0 + bb4.x - rm4.x) + bt4.x, 0.f);
    float z1 = fmaxf(g4.y * rsqrtf(rv4.y + 1e-5f) * (y1 + bb4.y - rm4.y) + bt4.y, 0.f);
    float z2 = fmaxf(g4.z * rsqrtf(rv4.z + 1e-5f) * (y2 + bb4.z - rm4.z) + bt4.z, 0.f);
    float z3 = fmaxf(g4.w * rsqrtf(rv4.w + 1e-5f) * (y3 + bb4.w - rm4.w) + bt4.w, 0.f);
    ushort4 o;
    o.x = f2b(z0); o.y = f2b(z1); o.z = f2b(z2); o.w = f2b(z3);
    *(ushort4*)(H + (size_t)node * 128 + l5 * 4) = o;
}

// ---- gates = qstar @ Wih^T + h @ Whh^T + bih + bhh ; tile [32 graphs x 64 rows] ----
__global__ __launch_bounds__(256) void k_gates(
    const float* __restrict__ qstar, const float* __restrict__ hbuf,
    const float* __restrict__ Wih, const float* __restrict__ Whh,
    const float* __restrict__ bih, const float* __restrict__ bhh,
    float* __restrict__ gates)
{
    __shared__ float X[32][384];
    int t = threadIdx.x;
    int gt = blockIdx.x & 7, rt = blockIdx.x >> 3;
    int G0 = gt * 32, R0 = rt * 64;
    const float4* q4 = (const float4*)qstar;  // [256][64] float4
    const float4* h4 = (const float4*)hbuf;   // [256][32] float4
#pragma unroll
    for (int i = 0; i < 12; i++) {
        int f = i * 256 + t;          // 0..3071
        int g = f / 96, c4 = f % 96;
        float4 v = (c4 < 64) ? q4[(size_t)(G0 + g) * 64 + c4]
                             : h4[(size_t)(G0 + g) * 32 + (c4 - 64)];
        ((float4*)X[g])[c4] = v;
    }
    __syncthreads();
    int r = t & 63, gq = t >> 6;
    int R = R0 + r;
    const float4* wi4 = (const float4*)(Wih + (size_t)R * 256);
    const float4* wh4 = (const float4*)(Whh + (size_t)R * 128);
    float bias = bih[R] + bhh[R];
    float acc[8];
#pragma unroll
    for (int j = 0; j < 8; j++) acc[j] = bias;
    for (int k = 0; k < 64; k++) {
        float4 wv = wi4[k];
#pragma unroll
        for (int j = 0; j < 8; j++) {
            float4 xv = ((const float4*)X[gq + 4 * j])[k];
            acc[j] += xv.x*wv.x + xv.y*wv.y + xv.z*wv.z + xv.w*wv.w;
        }
    }
    for (int k = 0; k < 32; k++) {
        float4 wv = wh4[k];
#pragma unroll
        for (int j = 0; j < 8; j++) {
            float4 xv = ((const float4*)X[gq + 4 * j])[64 + k];
            acc[j] += xv.x*wv.x + xv.y*wv.y + xv.z*wv.z + xv.w*wv.w;
        }
    }
#pragma unroll
    for (int j = 0; j < 8; j++)
        gates[(size_t)(G0 + gq + 4 * j) * 512 + R] = acc[j];
}

// ---- fused LSTM pointwise + online-softmax attention + qstar update ----
// do_lstm: 2 = step-0 bias-only LSTM (exact: qstar=0,h=0), 1 = gates-based.
__global__ __launch_bounds__(256) void k_attn2(
    const unsigned short* __restrict__ h2, const float* __restrict__ gates,
    const int* __restrict__ gptr,
    const float* __restrict__ bih, const float* __restrict__ bhh,
    float* __restrict__ hbuf, float* __restrict__ cbuf,
    float* __restrict__ qstar, int do_lstm)
{
    int b = blockIdx.x, t = threadIdx.x;
    int wave = t >> 6, lane = t & 63;
    __shared__ float hs[FD];
    __shared__ float wm[4], wd[4], red[4][FD];

    if (t < FD) {
        float c, h;
        if (do_lstm == 2) {
            float ig = bih[t] + bhh[t];
            float gg = bih[2 * FD + t] + bhh[2 * FD + t];
            float og = bih[3 * FD + t] + bhh[3 * FD + t];
            c = sigf(ig) * tanhf(gg);       // f-gate * c_prev(=0) dropped
            h = sigf(og) * tanhf(c);
        } else {
            const float* gr = gates + (size_t)b * 512;
            float ig = gr[t], fg = gr[FD + t], gg = gr[2 * FD + t], og = gr[3 * FD + t];
            c = sigf(fg) * cbuf[(size_t)b * FD + t] + sigf(ig) * tanhf(gg);
            h = sigf(og) * tanhf(c);
        }
        cbuf[(size_t)b * FD + t] = c;
        hbuf[(size_t)b * FD + t] = h;
        hs[t] = h;
    }
    __syncthreads();

    int start = gptr[b], end = gptr[b + 1];
    float2 q = ((const float2*)hs)[lane];
    const unsigned int* H2 = (const unsigned int*)h2;  // row = 64 uints
    float mw = -INFINITY, dw = 0.f, rx = 0.f, ry = 0.f;
    for (int n = start + wave; n < end; n += 4) {
        unsigned int u = H2[(size_t)n * 64 + lane];
        float vx = b2f(u & 0xFFFFu), vy = b2f(u >> 16);
        float e = vx * q.x + vy * q.y;
#pragma unroll
        for (int off = 32; off; off >>= 1) e += __shfl_xor(e, off);
        float mn = fmaxf(mw, e);
        float corr = __expf(mw - mn);     // first iter: exp(-inf)=0
        float a = __expf(e - mn);
        rx = rx * corr + a * vx;
        ry = ry * corr + a * vy;
        dw = dw * corr + a;
        mw = mn;
    }
    if (lane == 0) wm[wave] = mw;
    __syncthreads();
    float M = fmaxf(fmaxf(wm[0], wm[1]), fmaxf(wm[2], wm[3]));
    float cr = (M == -INFINITY) ? 0.f : __expf(mw - M);
    red[wave][2 * lane] = rx * cr;
    red[wave][2 * lane + 1] = ry * cr;
    if (lane == 0) wd[wave] = dw * cr;
    __syncthreads();
    if (t < FD) {
        float r = red[0][t] + red[1][t] + red[2][t] + red[3][t];
        float den = wd[0] + wd[1] + wd[2] + wd[3];
        float rn = (den > 0.f) ? r / den : 0.f;
        qstar[(size_t)b * 256 + t] = hs[t];
        qstar[(size_t)b * 256 + FD + t] = rn;
    }
}

// ---- final projection: out = qstar @ Wp^T + bp ; 2 graphs per block ----
__global__ __launch_bounds__(256) void k_proj(
    const float* __restrict__ qstar, const float* __restrict__ Wp,
    const float* __restrict__ bp, float* __restrict__ out)
{
    __shared__ float qs[2][256];
    int t = threadIdx.x;
    int b0 = blockIdx.x * 2;
    qs[0][t] = qstar[(size_t)b0 * 256 + t];
    qs[1][t] = qstar[(size_t)(b0 + 1) * 256 + t];
    __syncthreads();
    int g = t >> 7, d = t & 127;
    const float4* w4 = (const float4*)(Wp + (size_t)d * 256);
    const float4* q4 = (const float4*)qs[g];
    float acc = bp[d];
    for (int k = 0; k < 64; k++) {
        float4 wv = w4[k], qv = q4[k];
        acc += qv.x*wv.x + qv.y*wv.y + qv.z*wv.z + qv.w*wv.w;
    }
    out[(size_t)(b0 + g) * FD + d] = acc;
}

__global__ void k_zero_out(float* __restrict__ out, int n) {
    int i = blockIdx.x * blockDim.x + threadIdx.x;
    if (i < n) out[i] = 0.f;
}

extern "C" void kernel_launch(void* const* d_in, const int* in_sizes, int n_in,
                              void* d_out, int out_size, void* d_ws, size_t ws_size,
                              hipStream_t stream) {
    const float* x   = (const float*)d_in[0];
    const int*  ei    = (const int*)d_in[1];
    const int*  batch = (const int*)d_in[2];
    const float* W1l = (const float*)d_in[3];
    const float* b1l = (const float*)d_in[4];
    const float* W1r = (const float*)d_in[5];
    const float* g1  = (const float*)d_in[6];
    const float* be1 = (const float*)d_in[7];
    const float* rm1 = (const float*)d_in[8];
    const float* rv1 = (const float*)d_in[9];
    const float* W2l = (const float*)d_in[10];
    const float* b2l = (const float*)d_in[11];
    const float* W2r = (const float*)d_in[12];
    const float* g2  = (const float*)d_in[13];
    const float* be2 = (const float*)d_in[14];
    const float* rm2 = (const float*)d_in[15];
    const float* rv2 = (const float*)d_in[16];
    const float* Wih = (const float*)d_in[17];
    const float* Whh = (const float*)d_in[18];
    const float* bih = (const float*)d_in[19];
    const float* bhh = (const float*)d_in[20];
    const float* Wp  = (const float*)d_in[21];
    const float* bp  = (const float*)d_in[22];
    float* out = (float*)d_out;

    auto al = [](size_t s) { return (s + 255) & ~(size_t)255; };
    size_t off_dcnt = 0;
    size_t off_cur  = off_dcnt + al((size_t)NN * 4);
    size_t off_gptr = off_cur  + al((size_t)NN * 4);
    size_t off_rp   = off_gptr + al((size_t)(NG + 1) * 4);
    size_t off_bs   = off_rp   + al((size_t)(NN + 1) * 4);
    size_t off_bo   = off_bs   + al((size_t)64 * 4);
    size_t off_srcs = off_bo   + al((size_t)64 * 4);
    size_t off_h2b  = off_srcs + al((size_t)NE * 4);
    size_t off_h1b  = off_h2b  + al((size_t)NN * FD * 2);
    size_t off_Wb   = off_h1b  + al((size_t)NN * FD * 2);
    size_t off_C    = off_Wb   + al((size_t)2 * 256 * 128 * 2);
    size_t off_qs   = off_C    + al((size_t)NN * 256 * 2);
    size_t off_hb   = off_qs   + al((size_t)NG * 256 * 4);
    size_t off_cb   = off_hb   + al((size_t)NG * FD * 4);
    size_t off_gt   = off_cb   + al((size_t)NG * FD * 4);
    size_t need     = off_gt   + al((size_t)NG * 512 * 4);

    if (ws_size < need) {
        k_zero_out<<<(out_size + 255) / 256, 256, 0, stream>>>(out, out_size);
        return;
    }

    char* p = (char*)d_ws;
    int* dcnt    = (int*)(p + off_dcnt);
    int* cursor  = (int*)(p + off_cur);
    int* gptr    = (int*)(p + off_gptr);
    int* rowptr  = (int*)(p + off_rp);
    int* bsum    = (int*)(p + off_bs);
    int* boff    = (int*)(p + off_bo);
    int* srcs    = (int*)(p + off_srcs);
    unsigned short* h2b = (unsigned short*)(p + off_h2b);
    unsigned short* h1b = (unsigned short*)(p + off_h1b);
    unsigned short* Wb  = (unsigned short*)(p + off_Wb);
    unsigned short* C   = (unsigned short*)(p + off_C);
    float* qstar = (float*)(p + off_qs);
    float* hbuf  = (float*)(p + off_hb);
    float* cbuf  = (float*)(p + off_cb);
    float* gates = (float*)(p + off_gt);

    // memset covers dcnt + cursor (contiguous)
    hipMemsetAsync(p, 0, off_gptr, stream);

    // CSR build (gptr atomic-free; parallel 3-phase scan)
    k_hist4<<<NE / 1024, 256, 0, stream>>>(ei, dcnt);
    k_gptr<<<(NN + 255) / 256, 256, 0, stream>>>(batch, gptr);
    k_scan_part<<<40, 1024, 0, stream>>>(dcnt, bsum);
    k_scan_boff<<<1, 64, 0, stream>>>(bsum, boff, rowptr);
    k_scan_fin<<<40, 1024, 0, stream>>>(dcnt, boff, rowptr);
    k_permute<<<(NE + 255) / 256, 256, 0, stream>>>(ei, rowptr, cursor, srcs);

    // weight conversion (both layers)
    k_cvt_w<<<64, 256, 0, stream>>>(W1l, W1r, W2l, W2r, Wb);

    // layer 1: x (fp32, converted in k_mm) -> GEMM -> gather -> h1b
    k_mm<<<NN / 64, 256, 0, stream>>>(x, 1, Wb, C);
    k_gather2<<<NN / 8, 256, 0, stream>>>(C, srcs, rowptr, b1l, g1, be1, rm1, rv1, h1b);

    // layer 2: h1b -> GEMM -> gather -> h2b
    k_mm<<<NN / 64, 256, 0, stream>>>(h1b, 0, Wb + 32768, C);
    k_gather2<<<NN / 8, 256, 0, stream>>>(C, srcs, rowptr, b2l, g2, be2, rm2, rv2, h2b);

    // set2set (step-0 LSTM folded into first attn2; exact)
    k_attn2<<<NG, 256, 0, stream>>>(h2b, gates, gptr, bih, bhh, hbuf, cbuf, qstar, 2);
    for (int step = 1; step < 3; step++) {
        k_gates<<<64, 256, 0, stream>>>(qstar, hbuf, Wih, Whh, bih, bhh, gates);
        k_attn2<<<NG, 256, 0, stream>>>(h2b, gates, gptr, bih, bhh, hbuf, cbuf, qstar, 1);
    }
    k_proj<<<NG / 2, 256, 0, stream>>>(qstar, Wp, bp, out);
}